// Round 5
// baseline (1942.003 us; speedup 1.0000x reference)
//
#include <hip/hip_runtime.h>

#define BSZ 16
#define NNODE 1024
#define NT (BSZ*NNODE)      // 16384 total nodes
#define EG 131072            // graph edges (before self loops)
#define ET (EG+NT)           // 147456 edges incl self loops

typedef unsigned short bfu;  // raw bf16

__device__ __forceinline__ float b2f(unsigned u) { return __uint_as_float(u << 16); }
__device__ __forceinline__ bfu f2b(float f) {
  unsigned u = __float_as_uint(f);
  u += 0x7fffu + ((u >> 16) & 1u);
  return (bfu)(u >> 16);
}
__device__ __forceinline__ void unpack8(uint4 u, float* f) {
  f[0] = b2f(u.x & 0xffffu); f[1] = b2f(u.x >> 16);
  f[2] = b2f(u.y & 0xffffu); f[3] = b2f(u.y >> 16);
  f[4] = b2f(u.z & 0xffffu); f[5] = b2f(u.z >> 16);
  f[6] = b2f(u.w & 0xffffu); f[7] = b2f(u.w >> 16);
}
__device__ __forceinline__ void edge_sd(const int* __restrict__ ei, int e, int& s, int& d) {
  if (e < EG) { s = ei[e]; d = ei[EG + e]; } else { s = e - EG; d = e - EG; }
}
__device__ __forceinline__ void atomicMaxF(float* addr, float val) {
  unsigned* ua = reinterpret_cast<unsigned*>(addr);
  unsigned old = *ua;
  while (__uint_as_float(old) < val) {
    unsigned assumed = old;
    old = atomicCAS(ua, assumed, __float_as_uint(val));
    if (old == assumed) break;
  }
}

// ---------------- generic GEMM: A[M,K] @ W[K,Nc] (W f32), f32 accumulate ----------------
// ABF: A is bf16 (internal buffer) else f32 (external input).
// tile 128x128, 256 threads, 8x8 per thread.
// EPI 0: outb = acc
// EPI 1: outb = elu(acc + b1[c] + b2[c] + agg[r*aggld + c])
// EPI 2: outb = acc + b1[c] + b2[c] + 0.5*(agg[r*aggld+c] + agg[r*aggld+128+c])   (layer3 head-mean)
// EPI 3: outf = acc + resid[r*ldo + c]                                            (pre-LN f32)
template<int EPI, bool ABF>
__global__ __launch_bounds__(256)
void gemm_k(const void* __restrict__ Av, int lda,
            const float* __restrict__ W, int ldw, int K,
            bfu* __restrict__ outb, float* __restrict__ outf, int ldo,
            const float* __restrict__ b1, const float* __restrict__ b2,
            const float* __restrict__ agg, int aggld,
            const float* __restrict__ resid)
{
  __shared__ float As[16][132];
  __shared__ float Bs[16][128];
  const int tid = threadIdx.x;
  const int tx = tid & 15, ty = tid >> 4;
  const int r0 = blockIdx.y * 128, n0 = blockIdx.x * 128;

  float acc[8][8];
  #pragma unroll
  for (int i = 0; i < 8; ++i)
    #pragma unroll
    for (int j = 0; j < 8; ++j) acc[i][j] = 0.f;

  const int arow = tid >> 1, akc = (tid & 1) * 8;
  const int wrow = tid >> 4, wc = (tid & 15) * 8;

  for (int k0 = 0; k0 < K; k0 += 16) {
    float fa[8], fw[8];
    if (ABF) {
      const bfu* A = (const bfu*)Av;
      uint4 ua = *reinterpret_cast<const uint4*>(A + (size_t)(r0 + arow) * lda + k0 + akc);
      unpack8(ua, fa);
    } else {
      const float* A = (const float*)Av;
      const float4* ap = reinterpret_cast<const float4*>(A + (size_t)(r0 + arow) * lda + k0 + akc);
      float4 a0 = ap[0], a1 = ap[1];
      fa[0]=a0.x; fa[1]=a0.y; fa[2]=a0.z; fa[3]=a0.w;
      fa[4]=a1.x; fa[5]=a1.y; fa[6]=a1.z; fa[7]=a1.w;
    }
    {
      const float4* wp = reinterpret_cast<const float4*>(W + (size_t)(k0 + wrow) * ldw + n0 + wc);
      float4 w0 = wp[0], w1 = wp[1];
      fw[0]=w0.x; fw[1]=w0.y; fw[2]=w0.z; fw[3]=w0.w;
      fw[4]=w1.x; fw[5]=w1.y; fw[6]=w1.z; fw[7]=w1.w;
    }
    #pragma unroll
    for (int j = 0; j < 8; ++j) As[akc + j][arow] = fa[j];
    #pragma unroll
    for (int j = 0; j < 8; ++j) Bs[wrow][wc + j] = fw[j];
    __syncthreads();
    #pragma unroll
    for (int kk = 0; kk < 16; ++kk) {
      float a[8], b[8];
      float4 t0 = *(const float4*)&As[kk][ty * 8];
      float4 t1 = *(const float4*)&As[kk][ty * 8 + 4];
      a[0]=t0.x; a[1]=t0.y; a[2]=t0.z; a[3]=t0.w; a[4]=t1.x; a[5]=t1.y; a[6]=t1.z; a[7]=t1.w;
      float4 s0 = *(const float4*)&Bs[kk][tx * 8];
      float4 s1 = *(const float4*)&Bs[kk][tx * 8 + 4];
      b[0]=s0.x; b[1]=s0.y; b[2]=s0.z; b[3]=s0.w; b[4]=s1.x; b[5]=s1.y; b[6]=s1.z; b[7]=s1.w;
      #pragma unroll
      for (int i = 0; i < 8; ++i)
        #pragma unroll
        for (int j = 0; j < 8; ++j)
          acc[i][j] = fmaf(a[i], b[j], acc[i][j]);
    }
    __syncthreads();
  }

  #pragma unroll
  for (int i = 0; i < 8; ++i) {
    const int r = r0 + ty * 8 + i;
    #pragma unroll
    for (int j = 0; j < 8; ++j) {
      const int c = n0 + tx * 8 + j;
      float val = acc[i][j];
      if (EPI == 0) {
        outb[(size_t)r * ldo + c] = f2b(val);
      } else if (EPI == 1) {
        val += b1[c] + b2[c] + agg[(size_t)r * aggld + c];
        val = val > 0.f ? val : expm1f(val);
        outb[(size_t)r * ldo + c] = f2b(val);
      } else if (EPI == 2) {
        val += b1[c] + b2[c]
             + 0.5f * (agg[(size_t)r * aggld + c] + agg[(size_t)r * aggld + 128 + c]);
        outb[(size_t)r * ldo + c] = f2b(val);
      } else {
        val += resid[(size_t)r * ldo + c];
        outf[(size_t)r * ldo + c] = val;
      }
    }
  }
}

// ---------------- GAT alpha: per node per head dot(h, asrc), dot(h, adst) ----------------
template<int CP>   // per-head channels (256 or 128); heads=2
__global__ __launch_bounds__(256)
void alpha_k(const bfu* __restrict__ h, const float* __restrict__ asrc, const float* __restrict__ adst,
             float* __restrict__ av_s, float* __restrict__ av_d)
{
  const int n = blockIdx.x, tid = threadIdx.x;
  const int CT = CP * 2;
  float s0 = 0.f, s1 = 0.f, d0 = 0.f, d1 = 0.f;
  for (int c = tid; c < CT; c += 256) {
    float hv = b2f(h[(size_t)n * CT + c]);
    float as = asrc[c], ad = adst[c];
    if (c < CP) { s0 = fmaf(hv, as, s0); d0 = fmaf(hv, ad, d0); }
    else        { s1 = fmaf(hv, as, s1); d1 = fmaf(hv, ad, d1); }
  }
  #pragma unroll
  for (int off = 32; off; off >>= 1) {
    s0 += __shfl_xor(s0, off); s1 += __shfl_xor(s1, off);
    d0 += __shfl_xor(d0, off); d1 += __shfl_xor(d1, off);
  }
  __shared__ float red[4][4];
  const int w = tid >> 6, lane = tid & 63;
  if (lane == 0) { red[0][w] = s0; red[1][w] = s1; red[2][w] = d0; red[3][w] = d1; }
  __syncthreads();
  if (tid == 0) {
    av_s[n * 2 + 0] = red[0][0] + red[0][1] + red[0][2] + red[0][3];
    av_s[n * 2 + 1] = red[1][0] + red[1][1] + red[1][2] + red[1][3];
    av_d[n * 2 + 0] = red[2][0] + red[2][1] + red[2][2] + red[2][3];
    av_d[n * 2 + 1] = red[3][0] + red[3][1] + red[3][2] + red[3][3];
  }
}

__global__ void init_seg(float* segmax, float* segsum) {
  int i = blockIdx.x * 256 + threadIdx.x;
  if (i < NT * 2) { segmax[i] = -1e30f; segsum[i] = 0.f; }
}
__global__ void zero_i(int* p, int n) {
  int i = blockIdx.x * 256 + threadIdx.x;
  if (i < n) p[i] = 0;
}

__global__ void edge_max(const int* __restrict__ ei, const float* __restrict__ av_s,
                         const float* __restrict__ av_d, float* __restrict__ segmax) {
  int e = blockIdx.x * 256 + threadIdx.x;
  if (e >= ET) return;
  int s, d; edge_sd(ei, e, s, d);
  #pragma unroll
  for (int h = 0; h < 2; ++h) {
    float a = av_s[s * 2 + h] + av_d[d * 2 + h];
    a = a > 0.f ? a : 0.2f * a;
    atomicMaxF(&segmax[d * 2 + h], a);
  }
}

__global__ void edge_exp(const int* __restrict__ ei, const float* __restrict__ av_s,
                         const float* __restrict__ av_d, const float* __restrict__ segmax,
                         float* __restrict__ wbuf, float* __restrict__ segsum) {
  int e = blockIdx.x * 256 + threadIdx.x;
  if (e >= ET) return;
  int s, d; edge_sd(ei, e, s, d);
  #pragma unroll
  for (int h = 0; h < 2; ++h) {
    float a = av_s[s * 2 + h] + av_d[d * 2 + h];
    a = a > 0.f ? a : 0.2f * a;
    float ex = expf(a - segmax[d * 2 + h]);
    wbuf[e * 2 + h] = ex;
    atomicAdd(&segsum[d * 2 + h], ex);
  }
}

// ---------------- CSR build (by dst), reused across all 3 layers ----------------
__global__ void csr_count(const int* __restrict__ ei, int* __restrict__ deg) {
  int e = blockIdx.x * 256 + threadIdx.x;
  if (e >= ET) return;
  int s, d; edge_sd(ei, e, s, d);
  atomicAdd(&deg[d], 1);
}
__global__ __launch_bounds__(1024)
void csr_scan(const int* __restrict__ deg, int* __restrict__ rowptr, int* __restrict__ fillc) {
  __shared__ int sums[1024];
  const int t = threadIdx.x;
  const int base = t * 16;
  int loc[16]; int s = 0;
  #pragma unroll
  for (int k = 0; k < 16; ++k) { loc[k] = deg[base + k]; s += loc[k]; }
  sums[t] = s;
  __syncthreads();
  for (int off = 1; off < 1024; off <<= 1) {
    int v = (t >= off) ? sums[t - off] : 0;
    __syncthreads();
    sums[t] += v;
    __syncthreads();
  }
  int run = sums[t] - s;
  #pragma unroll
  for (int k = 0; k < 16; ++k) { rowptr[base + k] = run; fillc[base + k] = run; run += loc[k]; }
  if (t == 1023) rowptr[NT] = sums[1023];
}
__global__ void csr_fill(const int* __restrict__ ei, int* __restrict__ fillc, int* __restrict__ eids) {
  int e = blockIdx.x * 256 + threadIdx.x;
  if (e >= ET) return;
  int s, d; edge_sd(ei, e, s, d);
  int pos = atomicAdd(&fillc[d], 1);
  eids[pos] = e;
}

// ---------------- aggregation: node-parallel gather ----------------
template<int CT>  // 512 (layers 1/2) or 256 (layer 3)
__global__ __launch_bounds__(256)
void agg_k(const int* __restrict__ rowptr, const int* __restrict__ eids, const int* __restrict__ ei,
           const bfu* __restrict__ h, const float* __restrict__ wbuf,
           const float* __restrict__ segsum, float* __restrict__ agg)
{
  const int n = blockIdx.x, tid = threadIdx.x;
  const float inv0 = 1.f / (segsum[n * 2 + 0] + 1e-16f);
  const float inv1 = 1.f / (segsum[n * 2 + 1] + 1e-16f);
  float a0 = 0.f, a1 = 0.f;
  const int beg = rowptr[n], end = rowptr[n + 1];
  for (int idx = beg; idx < end; ++idx) {
    int e = eids[idx];
    int s, d; edge_sd(ei, e, s, d);
    float w0 = wbuf[e * 2 + 0] * inv0;
    float w1 = wbuf[e * 2 + 1] * inv1;
    if (CT == 512) {
      a0 = fmaf(w0, b2f(h[(size_t)s * 512 + tid]), a0);
      a1 = fmaf(w1, b2f(h[(size_t)s * 512 + 256 + tid]), a1);
    } else {
      float wv = tid < 128 ? w0 : w1;
      a0 = fmaf(wv, b2f(h[(size_t)s * 256 + tid]), a0);
    }
  }
  if (CT == 512) {
    agg[(size_t)n * 512 + tid] = a0;
    agg[(size_t)n * 512 + 256 + tid] = a1;
  } else {
    agg[(size_t)n * 256 + tid] = a0;
  }
}

// ---------------- attention: per (b,h) 8 q-rows per block ----------------
#define AROWS 8
__global__ __launch_bounds__(256)
void attn_k(const bfu* __restrict__ qh, const bfu* __restrict__ kh, const bfu* __restrict__ vh,
            float* __restrict__ attn_out, bfu* __restrict__ catb)
{
  __shared__ float Qs[AROWS][64];
  __shared__ float Ss[AROWS][NNODE];
  const int tid = threadIdx.x;
  const int bh = blockIdx.y, b = bh >> 1, h = bh & 1;
  const int r0 = blockIdx.x * AROWS;
  const size_t base = (size_t)b * NNODE;

  for (int idx = tid; idx < AROWS * 64; idx += 256) {
    int i = idx >> 6, d = idx & 63;
    Qs[i][d] = 0.125f * b2f(qh[(base + r0 + i) * 128 + h * 64 + d]);
  }
  __syncthreads();

  for (int j = tid; j < NNODE; j += 256) {
    float kreg[64];
    const uint4* kp = reinterpret_cast<const uint4*>(kh + (base + j) * 128 + h * 64);
    #pragma unroll
    for (int m = 0; m < 8; ++m) { uint4 u = kp[m]; unpack8(u, &kreg[m * 8]); }
    #pragma unroll
    for (int i = 0; i < AROWS; ++i) {
      float acc = 0.f;
      #pragma unroll
      for (int d4 = 0; d4 < 16; ++d4) {
        float4 qv = *(const float4*)&Qs[i][d4 * 4];
        acc = fmaf(qv.x, kreg[d4 * 4 + 0], acc);
        acc = fmaf(qv.y, kreg[d4 * 4 + 1], acc);
        acc = fmaf(qv.z, kreg[d4 * 4 + 2], acc);
        acc = fmaf(qv.w, kreg[d4 * 4 + 3], acc);
      }
      Ss[i][j] = acc;
    }
  }
  __syncthreads();

  const int w = tid >> 6, lane = tid & 63;
  for (int i = w; i < AROWS; i += 4) {
    float mx = -1e30f;
    for (int jj = lane; jj < NNODE; jj += 64) mx = fmaxf(mx, Ss[i][jj]);
    #pragma unroll
    for (int off = 32; off; off >>= 1) mx = fmaxf(mx, __shfl_xor(mx, off));
    float sum = 0.f;
    for (int jj = lane; jj < NNODE; jj += 64) {
      float e = expf(Ss[i][jj] - mx);
      Ss[i][jj] = e; sum += e;
    }
    #pragma unroll
    for (int off = 32; off; off >>= 1) sum += __shfl_xor(sum, off);
    float inv = 1.f / sum;
    size_t obase = ((size_t)bh * NNODE + (r0 + i)) * NNODE;
    for (int jj = lane; jj < NNODE; jj += 64) {
      float p = Ss[i][jj] * inv;
      Ss[i][jj] = p;
      attn_out[obase + jj] = p;     // f32 output
    }
  }
  __syncthreads();

  const int d = tid & 63, ig = tid >> 6;
  float acc0 = 0.f, acc1 = 0.f;
  for (int j = 0; j < NNODE; j += 4) {
    float4 p0 = *(const float4*)&Ss[ig * 2 + 0][j];
    float4 p1 = *(const float4*)&Ss[ig * 2 + 1][j];
    #pragma unroll
    for (int jj = 0; jj < 4; ++jj) {
      float vvv = b2f(vh[(base + j + jj) * 128 + h * 64 + d]);
      acc0 = fmaf(((const float*)&p0)[jj], vvv, acc0);
      acc1 = fmaf(((const float*)&p1)[jj], vvv, acc1);
    }
  }
  {
    size_t r = base + r0 + ig * 2;
    catb[(r + 0) * 256 + 128 + h * 64 + d] = f2b(acc0);
    catb[(r + 1) * 256 + 128 + h * 64 + d] = f2b(acc1);
  }
}

// ---------------- LayerNorm over 256, write f32 y ----------------
__global__ __launch_bounds__(256)
void ln_k(const float* __restrict__ x, const float* __restrict__ g, const float* __restrict__ bta,
          float* __restrict__ y)
{
  const int r = blockIdx.x, tid = threadIdx.x;
  float v = x[(size_t)r * 256 + tid];
  float s = v;
  #pragma unroll
  for (int off = 32; off; off >>= 1) s += __shfl_xor(s, off);
  __shared__ float red[4], red2[4];
  const int w = tid >> 6, lane = tid & 63;
  if (lane == 0) red[w] = s;
  __syncthreads();
  float mu = (red[0] + red[1] + red[2] + red[3]) * (1.f / 256.f);
  float dv = v - mu;
  float q2 = dv * dv;
  #pragma unroll
  for (int off = 32; off; off >>= 1) q2 += __shfl_xor(q2, off);
  if (lane == 0) red2[w] = q2;
  __syncthreads();
  float var = (red2[0] + red2[1] + red2[2] + red2[3]) * (1.f / 256.f);
  float o = dv * rsqrtf(var + 1e-6f) * g[tid] + bta[tid];
  y[(size_t)r * 256 + tid] = o;     // f32 output
}

extern "C" void kernel_launch(void* const* d_in, const int* in_sizes, int n_in,
                              void* d_out, int out_size, void* d_ws, size_t ws_size,
                              hipStream_t stream)
{
  const float* q   = (const float*)d_in[0];
  const float* kin = (const float*)d_in[1];
  const float* vin = (const float*)d_in[2];
  const int*   ei  = (const int*)d_in[3];
  const float* Wq  = (const float*)d_in[4];
  const float* Wk  = (const float*)d_in[5];
  const float* Wv  = (const float*)d_in[6];
  const float* Wfc = (const float*)d_in[7];
  const float* g1W = (const float*)d_in[8],  *g1as = (const float*)d_in[9],  *g1ad = (const float*)d_in[10], *g1b = (const float*)d_in[11];
  const float* l1W = (const float*)d_in[12], *l1b = (const float*)d_in[13];
  const float* g2W = (const float*)d_in[14], *g2as = (const float*)d_in[15], *g2ad = (const float*)d_in[16], *g2b = (const float*)d_in[17];
  const float* l2W = (const float*)d_in[18], *l2b = (const float*)d_in[19];
  const float* g3W = (const float*)d_in[20], *g3as = (const float*)d_in[21], *g3ad = (const float*)d_in[22], *g3b = (const float*)d_in[23];
  const float* l3W = (const float*)d_in[24], *l3b = (const float*)d_in[25];
  const float* lng = (const float*)d_in[26], *lnb = (const float*)d_in[27];

  // ---- d_out regions (FLOAT32 output: reference computes in f32) ----
  float* ybuf = (float*)d_out;                          // y region: NT*256 f32 = 16.78 MB
  float* attn_out = ybuf + (size_t)NT * 256;            // attn region: 33.55M f32 = 134.2 MB

  // catb (bf16 scratch [NT][256] = 8.39 MB) lives in the first half of the y
  // region. Fully written (gemm<2> cols 0-127, attn_k cols 128-255) before
  // gemm<3> reads it; ln_k overwrites the region with f32 y afterwards.
  bfu* catb = (bfu*)d_out;

  // GAT scratch at the START of the attn region (36.1 MB < 134.2 MB); all of
  // it is dead before attn_k writes the attn output over it.
  char* ap = (char*)attn_out;
  auto take_a = [&](size_t bytes) -> void* {
    void* r = (void*)ap;
    ap += (bytes + 255) & ~(size_t)255;
    return r;
  };
  float* aggb   = (float*)take_a((size_t)NT * 512 * 4);   // 33.55 MB
  float* avs    = (float*)take_a((size_t)NT * 2 * 4);
  float* avd    = (float*)take_a((size_t)NT * 2 * 4);
  float* segmax = (float*)take_a((size_t)NT * 2 * 4);
  float* segsum = (float*)take_a((size_t)NT * 2 * 4);
  float* wbuf   = (float*)take_a((size_t)ET * 2 * 4);     // 1.18 MB
  int* deg    = (int*)take_a((size_t)NT * 4);
  int* rowptr = (int*)take_a((size_t)(NT + 1) * 4);
  int* fillc  = (int*)take_a((size_t)NT * 4);
  int* eids   = (int*)take_a((size_t)ET * 4);

  // ---- d_ws: only the three big activations (50.3 MB total) ----
  char* p = (char*)d_ws;
  auto take = [&](size_t bytes) -> void* {
    void* r = (void*)p;
    p += (bytes + 255) & ~(size_t)255;
    return r;
  };
  bfu* hbuf = (bfu*)take((size_t)NT * 512 * 2);   // 16.78 MB; layer h-features
  bfu* x1   = (bfu*)take((size_t)NT * 512 * 2);   // 16.78 MB
  bfu* x2   = (bfu*)take((size_t)NT * 512 * 2);   // 16.78 MB

  // Aliases (liveness-checked):
  //  qh/khb/vhb occupy hbuf space: hbuf dead after layer-3 agg; projections run after GAT.
  //  They must survive attn_k -> they live in d_ws, untouched by attn region. OK.
  bfu* qh  = hbuf;
  bfu* khb = hbuf + (size_t)NT * 128;
  bfu* vhb = hbuf + (size_t)NT * 256;
  //  prelng (f32 NT*256 = 16.78 MB) aliases x1: x1 dead after layer-2 lin gemm;
  //  read by ln_k at the very end (d_ws region -> safe from attn_k).
  float* prelng = (float*)x1;

  const int EB = (ET + 255) / 256;
  const int SB = (NT * 2 + 255) / 256;

  // CSR build (same graph for all 3 layers)
  zero_i<<<(NT + 255) / 256, 256, 0, stream>>>(deg, NT);
  csr_count<<<EB, 256, 0, stream>>>(ei, deg);
  csr_scan<<<1, 1024, 0, stream>>>(deg, rowptr, fillc);
  csr_fill<<<EB, 256, 0, stream>>>(ei, fillc, eids);

  // ---- GAT layer 1 (in: q Nx256 -> out x1 Nx512) ----
  gemm_k<0,false><<<dim3(4, 128), 256, 0, stream>>>(q, 256, g1W, 512, 256, hbuf, nullptr, 512, nullptr, nullptr, nullptr, 0, nullptr);
  alpha_k<256><<<NT, 256, 0, stream>>>(hbuf, g1as, g1ad, avs, avd);
  init_seg<<<SB, 256, 0, stream>>>(segmax, segsum);
  edge_max<<<EB, 256, 0, stream>>>(ei, avs, avd, segmax);
  edge_exp<<<EB, 256, 0, stream>>>(ei, avs, avd, segmax, wbuf, segsum);
  agg_k<512><<<NT, 256, 0, stream>>>(rowptr, eids, ei, hbuf, wbuf, segsum, aggb);
  gemm_k<1,false><<<dim3(4, 128), 256, 0, stream>>>(q, 256, l1W, 512, 256, x1, nullptr, 512, l1b, g1b, aggb, 512, nullptr);

  // ---- GAT layer 2 (in: x1 Nx512 -> out x2 Nx512) ----
  gemm_k<0,true><<<dim3(4, 128), 256, 0, stream>>>(x1, 512, g2W, 512, 512, hbuf, nullptr, 512, nullptr, nullptr, nullptr, 0, nullptr);
  alpha_k<256><<<NT, 256, 0, stream>>>(hbuf, g2as, g2ad, avs, avd);
  init_seg<<<SB, 256, 0, stream>>>(segmax, segsum);
  edge_max<<<EB, 256, 0, stream>>>(ei, avs, avd, segmax);
  edge_exp<<<EB, 256, 0, stream>>>(ei, avs, avd, segmax, wbuf, segsum);
  agg_k<512><<<NT, 256, 0, stream>>>(rowptr, eids, ei, hbuf, wbuf, segsum, aggb);
  gemm_k<1,true><<<dim3(4, 128), 256, 0, stream>>>(x1, 512, l2W, 512, 512, x2, nullptr, 512, l2b, g2b, aggb, 512, nullptr);
  // x1 now dead.

  // ---- GAT layer 3 (in: x2 Nx512 -> head-mean -> catb[:, 0:128]) ----
  gemm_k<0,true><<<dim3(2, 128), 256, 0, stream>>>(x2, 512, g3W, 256, 512, hbuf, nullptr, 256, nullptr, nullptr, nullptr, 0, nullptr);
  alpha_k<128><<<NT, 256, 0, stream>>>(hbuf, g3as, g3ad, avs, avd);
  init_seg<<<SB, 256, 0, stream>>>(segmax, segsum);
  edge_max<<<EB, 256, 0, stream>>>(ei, avs, avd, segmax);
  edge_exp<<<EB, 256, 0, stream>>>(ei, avs, avd, segmax, wbuf, segsum);
  agg_k<256><<<NT, 256, 0, stream>>>(rowptr, eids, ei, hbuf, wbuf, segsum, aggb);
  gemm_k<2,true><<<dim3(1, 128), 256, 0, stream>>>(x2, 512, l3W, 128, 512, catb, nullptr, 256, l3b, g3b, aggb, 256, nullptr);
  // hbuf now dead -> reuse for qh/khb/vhb.  GAT scratch (attn region) now dead.

  // ---- q/k/v projections (no bias) ----
  gemm_k<0,false><<<dim3(1, 128), 256, 0, stream>>>(q,   256, Wq, 128, 256, qh,  nullptr, 128, nullptr, nullptr, nullptr, 0, nullptr);
  gemm_k<0,false><<<dim3(1, 128), 256, 0, stream>>>(kin, 256, Wk, 128, 256, khb, nullptr, 128, nullptr, nullptr, nullptr, 0, nullptr);
  gemm_k<0,false><<<dim3(1, 128), 256, 0, stream>>>(vin, 256, Wv, 128, 256, vhb, nullptr, 128, nullptr, nullptr, nullptr, 0, nullptr);

  // ---- attention: writes attn (f32, d_out attn region) + catb[:, 128:256] ----
  attn_k<<<dim3(NNODE / AROWS, BSZ * 2), 256, 0, stream>>>(qh, khb, vhb, attn_out, catb);

  // ---- final FC + residual + LN ----
  gemm_k<3,true><<<dim3(2, 128), 256, 0, stream>>>(catb, 256, Wfc, 256, 256, nullptr, prelng, 256, nullptr, nullptr, nullptr, 0, q);
  ln_k<<<NT, 256, 0, stream>>>(prelng, lng, lnb, ybuf);
}

// Round 6
// 675.259 us; speedup vs baseline: 2.8759x; 2.8759x over previous
//
#include <hip/hip_runtime.h>

#define BSZ 16
#define NNODE 1024
#define NT (BSZ*NNODE)      // 16384 total nodes
#define EG 131072            // graph edges (before self loops)
#define ET (EG+NT)           // 147456 edges incl self loops

typedef unsigned short bfu;  // raw bf16
typedef __attribute__((ext_vector_type(8))) short short8v;   // 8 bf16 (4 VGPRs)
typedef __attribute__((ext_vector_type(4))) float f32x4;     // MFMA accum

__device__ __forceinline__ float b2f(unsigned u) { return __uint_as_float(u << 16); }
__device__ __forceinline__ bfu f2b(float f) {
  unsigned u = __float_as_uint(f);
  u += 0x7fffu + ((u >> 16) & 1u);
  return (bfu)(u >> 16);
}
__device__ __forceinline__ void edge_sd(const int* __restrict__ ei, int e, int& s, int& d) {
  if (e < EG) { s = ei[e]; d = ei[EG + e]; } else { s = e - EG; d = e - EG; }
}
__device__ __forceinline__ void atomicMaxF(float* addr, float val) {
  unsigned* ua = reinterpret_cast<unsigned*>(addr);
  unsigned old = *ua;
  while (__uint_as_float(old) < val) {
    unsigned assumed = old;
    old = atomicCAS(ua, assumed, __float_as_uint(val));
    if (old == assumed) break;
  }
}

// ============ MFMA GEMM: C[M,N] = A[M,K](bf16) x Bt[N,K](bf16)^T ============
// 128x128 tile, BK=32, 256 threads = 4 waves (2x2 of 64x64), 16x16x32 bf16 MFMA.
// Fragment mapping (gfx950, guide-verified D map): A: row=l&15, k=(l>>4)*8+i;
// B(t): col-row=l&15, same k; D: col=l&15, row=(l>>4)*4+i.
// EPI 0: bf16 out = acc
// EPI 1: bf16 out = elu(acc + b1[c] + b2[c] + agg[r*aggld+c])
// EPI 2: bf16 out = acc + b1[c] + b2[c] + 0.5*(agg[r*aggld+c]+agg[r*aggld+128+c])
// EPI 3: f32 out  = acc + resid[r*ldo+c]
// EPI 4: f32 out  = acc                      (attn scores, batched)
// EPI 5: bf16 vt[bh][d][node] transposed-V   (projection)
// EPI 6: bf16 qh2/khb2 [bh][node][64]        (projection)
template<int EPI>
__global__ __launch_bounds__(256)
void mgemm(const bfu* __restrict__ A, int lda, long long sA,
           const bfu* __restrict__ Bt, int ldb, long long sB,
           int K,
           bfu* __restrict__ outb, float* __restrict__ outf, int ldo, long long sO,
           const float* __restrict__ b1, const float* __restrict__ b2,
           const float* __restrict__ agg, int aggld,
           const float* __restrict__ resid)
{
  __shared__ bfu As[128 * 32];
  __shared__ bfu Bs[128 * 32];
  const int tid = threadIdx.x;
  const int z = blockIdx.z;
  const int n0 = blockIdx.x * 128, r0 = blockIdx.y * 128;
  const bfu* Az = A + (size_t)z * sA;
  const bfu* Bz = Bt + (size_t)z * sB;

  const int w = tid >> 6, l = tid & 63;
  const int wr = w >> 1, wc = w & 1;
  const int lr = l & 15;
  const int lk = (l >> 4) * 8;

  f32x4 acc[4][4] = {};

  // staging: chunk c (0..511) = 16B of [row=c>>2][k=(c&3)*8]; thread t owns c=t and c=t+256
  const int c0 = tid, c1 = tid + 256;
  const int ar0 = c0 >> 2, ak0 = (c0 & 3) * 8;
  const int ar1 = c1 >> 2, ak1 = (c1 & 3) * 8;

  short8v ra0 = *(const short8v*)(Az + (size_t)(r0 + ar0) * lda + ak0);
  short8v ra1 = *(const short8v*)(Az + (size_t)(r0 + ar1) * lda + ak1);
  short8v rb0 = *(const short8v*)(Bz + (size_t)(n0 + ar0) * ldb + ak0);
  short8v rb1 = *(const short8v*)(Bz + (size_t)(n0 + ar1) * ldb + ak1);

  for (int k0 = 0; k0 < K; k0 += 32) {
    __syncthreads();
    *(short8v*)(As + c0 * 8) = ra0;
    *(short8v*)(As + c1 * 8) = ra1;
    *(short8v*)(Bs + c0 * 8) = rb0;
    *(short8v*)(Bs + c1 * 8) = rb1;
    __syncthreads();
    const int kn = k0 + 32;
    if (kn < K) {   // prefetch next K-step while MFMAs run
      ra0 = *(const short8v*)(Az + (size_t)(r0 + ar0) * lda + kn + ak0);
      ra1 = *(const short8v*)(Az + (size_t)(r0 + ar1) * lda + kn + ak1);
      rb0 = *(const short8v*)(Bz + (size_t)(n0 + ar0) * ldb + kn + ak0);
      rb1 = *(const short8v*)(Bz + (size_t)(n0 + ar1) * ldb + kn + ak1);
    }
    short8v af[4], bfr[4];
    #pragma unroll
    for (int mi = 0; mi < 4; ++mi)
      af[mi] = *(const short8v*)(As + (wr * 64 + mi * 16 + lr) * 32 + lk);
    #pragma unroll
    for (int ni = 0; ni < 4; ++ni)
      bfr[ni] = *(const short8v*)(Bs + (wc * 64 + ni * 16 + lr) * 32 + lk);
    #pragma unroll
    for (int mi = 0; mi < 4; ++mi)
      #pragma unroll
      for (int ni = 0; ni < 4; ++ni)
        acc[mi][ni] = __builtin_amdgcn_mfma_f32_16x16x32_bf16(af[mi], bfr[ni], acc[mi][ni], 0, 0, 0);
  }

  const int rr = (l >> 4) * 4;
  #pragma unroll
  for (int mi = 0; mi < 4; ++mi) {
    #pragma unroll
    for (int ni = 0; ni < 4; ++ni) {
      #pragma unroll
      for (int i = 0; i < 4; ++i) {
        const int r = r0 + wr * 64 + mi * 16 + rr + i;
        const int cc = n0 + wc * 64 + ni * 16 + lr;
        float val = acc[mi][ni][i];
        if (EPI == 0) {
          outb[(size_t)z * sO + (size_t)r * ldo + cc] = f2b(val);
        } else if (EPI == 1) {
          val += b1[cc] + b2[cc] + agg[(size_t)r * aggld + cc];
          val = val > 0.f ? val : expm1f(val);
          outb[(size_t)r * ldo + cc] = f2b(val);
        } else if (EPI == 2) {
          val += b1[cc] + b2[cc]
               + 0.5f * (agg[(size_t)r * aggld + cc] + agg[(size_t)r * aggld + 128 + cc]);
          outb[(size_t)r * ldo + cc] = f2b(val);
        } else if (EPI == 3) {
          outf[(size_t)r * ldo + cc] = val + resid[(size_t)r * ldo + cc];
        } else if (EPI == 4) {
          outf[(size_t)z * sO + (size_t)r * ldo + cc] = val;
        } else if (EPI == 5) {
          // vt[bh][d][node]: bh=(r>>10)*2+(cc>>6), d=cc&63, node=r&1023
          outb[((size_t)((r >> 10) * 2 + (cc >> 6))) * 65536 + (size_t)(cc & 63) * 1024 + (r & 1023)] = f2b(val);
        } else { // EPI == 6: qh2/khb2 [bh][node][64]
          outb[((size_t)((r >> 10) * 2 + (cc >> 6))) * 65536 + (size_t)(r & 1023) * 64 + (cc & 63)] = f2b(val);
        }
      }
    }
  }
}

// ============ PV: O[1024,64] = P(f32)[1024,1024] x V[1024,64], per bh ============
// 64-row tile, 4 waves (16 rows each), Bt = vt[bh][d][node].
__global__ __launch_bounds__(256)
void pv_k(const float* __restrict__ P, const bfu* __restrict__ vt, bfu* __restrict__ catb)
{
  __shared__ float Asf[64 * 32];
  __shared__ bfu Bs[64 * 32];
  const int tid = threadIdx.x;
  const int bh = blockIdx.y, rt0 = blockIdx.x * 64;
  const float* Pz = P + (size_t)bh * 1048576 + (size_t)rt0 * 1024;
  const bfu* Bz = vt + (size_t)bh * 65536;
  const int w = tid >> 6, l = tid & 63;
  const int lr = l & 15, lk = (l >> 4) * 8;

  f32x4 acc[4] = {};

  // A: 64 rows x 32 f32 = 512 x 16B chunks -> 2/thread; chunk c: row=c>>3, koff=(c&7)*4
  // B: 64 rows x 32 bf16 = 256 x 16B chunks -> 1/thread; chunk c: row=c>>2, koff=(c&3)*8
  const int ca0 = tid, ca1 = tid + 256;
  float4 pa0 = *(const float4*)(Pz + (size_t)(ca0 >> 3) * 1024 + (ca0 & 7) * 4);
  float4 pa1 = *(const float4*)(Pz + (size_t)(ca1 >> 3) * 1024 + (ca1 & 7) * 4);
  short8v pb = *(const short8v*)(Bz + (size_t)(tid >> 2) * 1024 + (tid & 3) * 8);

  for (int k0 = 0; k0 < 1024; k0 += 32) {
    __syncthreads();
    *(float4*)(Asf + ca0 * 4) = pa0;
    *(float4*)(Asf + ca1 * 4) = pa1;
    *(short8v*)(Bs + tid * 8) = pb;
    __syncthreads();
    const int kn = k0 + 32;
    if (kn < 1024) {
      pa0 = *(const float4*)(Pz + (size_t)(ca0 >> 3) * 1024 + kn + (ca0 & 7) * 4);
      pa1 = *(const float4*)(Pz + (size_t)(ca1 >> 3) * 1024 + kn + (ca1 & 7) * 4);
      pb = *(const short8v*)(Bz + (size_t)(tid >> 2) * 1024 + kn + (tid & 3) * 8);
    }
    short8v bfr[4];
    #pragma unroll
    for (int ni = 0; ni < 4; ++ni)
      bfr[ni] = *(const short8v*)(Bs + (ni * 16 + lr) * 32 + lk);
    const float* apf = Asf + (w * 16 + lr) * 32 + lk;
    float4 u = *(const float4*)apf;
    float4 v = *(const float4*)(apf + 4);
    short8v af;
    af[0] = (short)f2b(u.x); af[1] = (short)f2b(u.y); af[2] = (short)f2b(u.z); af[3] = (short)f2b(u.w);
    af[4] = (short)f2b(v.x); af[5] = (short)f2b(v.y); af[6] = (short)f2b(v.z); af[7] = (short)f2b(v.w);
    #pragma unroll
    for (int ni = 0; ni < 4; ++ni)
      acc[ni] = __builtin_amdgcn_mfma_f32_16x16x32_bf16(af, bfr[ni], acc[ni], 0, 0, 0);
  }

  const int b = bh >> 1, h = bh & 1;
  const int rr = (l >> 4) * 4;
  #pragma unroll
  for (int ni = 0; ni < 4; ++ni) {
    #pragma unroll
    for (int i = 0; i < 4; ++i) {
      const int qn = rt0 + w * 16 + rr + i;
      const int d = ni * 16 + lr;
      catb[((size_t)(b * 1024 + qn)) * 256 + 128 + h * 64 + d] = f2b(acc[ni][i]);
    }
  }
}

// ============ row softmax, in place on f32 [32768][1024] ============
__global__ __launch_bounds__(256)
void sm_k(float* __restrict__ Sf)
{
  const int w = threadIdx.x >> 6, l = threadIdx.x & 63;
  const size_t R = (size_t)blockIdx.x * 4 + w;
  float* row = Sf + R * 1024;
  float4 vv[4];
  float mx = -1e30f;
  #pragma unroll
  for (int j = 0; j < 4; ++j) {
    vv[j] = *(float4*)(row + j * 256 + l * 4);
    mx = fmaxf(mx, fmaxf(fmaxf(vv[j].x, vv[j].y), fmaxf(vv[j].z, vv[j].w)));
  }
  #pragma unroll
  for (int off = 32; off; off >>= 1) mx = fmaxf(mx, __shfl_xor(mx, off));
  float sum = 0.f;
  #pragma unroll
  for (int j = 0; j < 4; ++j) {
    vv[j].x = expf(vv[j].x - mx); vv[j].y = expf(vv[j].y - mx);
    vv[j].z = expf(vv[j].z - mx); vv[j].w = expf(vv[j].w - mx);
    sum += vv[j].x + vv[j].y + vv[j].z + vv[j].w;
  }
  #pragma unroll
  for (int off = 32; off; off >>= 1) sum += __shfl_xor(sum, off);
  const float inv = 1.f / sum;
  #pragma unroll
  for (int j = 0; j < 4; ++j) {
    vv[j].x *= inv; vv[j].y *= inv; vv[j].z *= inv; vv[j].w *= inv;
    *(float4*)(row + j * 256 + l * 4) = vv[j];
  }
}

// ============ conversions ============
// W[K][N] f32 -> Wt[N][K] bf16 (with scale)
__global__ void wconv_k(const float* __restrict__ W, bfu* __restrict__ Wt, int K, int N, float scale)
{
  const int idx = blockIdx.x * 256 + threadIdx.x;
  if (idx >= N * K) return;
  const int n = idx / K, k = idx - n * K;
  Wt[idx] = f2b(W[(size_t)k * N + n] * scale);
}
// f32 -> bf16 same layout, 4 at a time
__global__ void aconv_k(const float* __restrict__ x, bfu* __restrict__ y, int n4)
{
  const int i = blockIdx.x * 256 + threadIdx.x;
  if (i >= n4) return;
  float4 v = ((const float4*)x)[i];
  uint2 o;
  o.x = (unsigned)f2b(v.x) | ((unsigned)f2b(v.y) << 16);
  o.y = (unsigned)f2b(v.z) | ((unsigned)f2b(v.w) << 16);
  ((uint2*)y)[i] = o;
}

// ---------------- GAT alpha ----------------
template<int CP>
__global__ __launch_bounds__(256)
void alpha_k(const bfu* __restrict__ h, const float* __restrict__ asrc, const float* __restrict__ adst,
             float* __restrict__ av_s, float* __restrict__ av_d)
{
  const int n = blockIdx.x, tid = threadIdx.x;
  const int CT = CP * 2;
  float s0 = 0.f, s1 = 0.f, d0 = 0.f, d1 = 0.f;
  for (int c = tid; c < CT; c += 256) {
    float hv = b2f(h[(size_t)n * CT + c]);
    float as = asrc[c], ad = adst[c];
    if (c < CP) { s0 = fmaf(hv, as, s0); d0 = fmaf(hv, ad, d0); }
    else        { s1 = fmaf(hv, as, s1); d1 = fmaf(hv, ad, d1); }
  }
  #pragma unroll
  for (int off = 32; off; off >>= 1) {
    s0 += __shfl_xor(s0, off); s1 += __shfl_xor(s1, off);
    d0 += __shfl_xor(d0, off); d1 += __shfl_xor(d1, off);
  }
  __shared__ float red[4][4];
  const int w = tid >> 6, lane = tid & 63;
  if (lane == 0) { red[0][w] = s0; red[1][w] = s1; red[2][w] = d0; red[3][w] = d1; }
  __syncthreads();
  if (tid == 0) {
    av_s[n * 2 + 0] = red[0][0] + red[0][1] + red[0][2] + red[0][3];
    av_s[n * 2 + 1] = red[1][0] + red[1][1] + red[1][2] + red[1][3];
    av_d[n * 2 + 0] = red[2][0] + red[2][1] + red[2][2] + red[2][3];
    av_d[n * 2 + 1] = red[3][0] + red[3][1] + red[3][2] + red[3][3];
  }
}

__global__ void init_seg(float* segmax, float* segsum) {
  int i = blockIdx.x * 256 + threadIdx.x;
  if (i < NT * 2) { segmax[i] = -1e30f; segsum[i] = 0.f; }
}
__global__ void zero_i(int* p, int n) {
  int i = blockIdx.x * 256 + threadIdx.x;
  if (i < n) p[i] = 0;
}
__global__ void edge_max(const int* __restrict__ ei, const float* __restrict__ av_s,
                         const float* __restrict__ av_d, float* __restrict__ segmax) {
  int e = blockIdx.x * 256 + threadIdx.x;
  if (e >= ET) return;
  int s, d; edge_sd(ei, e, s, d);
  #pragma unroll
  for (int h = 0; h < 2; ++h) {
    float a = av_s[s * 2 + h] + av_d[d * 2 + h];
    a = a > 0.f ? a : 0.2f * a;
    atomicMaxF(&segmax[d * 2 + h], a);
  }
}
__global__ void edge_exp(const int* __restrict__ ei, const float* __restrict__ av_s,
                         const float* __restrict__ av_d, const float* __restrict__ segmax,
                         float* __restrict__ wbuf, float* __restrict__ segsum) {
  int e = blockIdx.x * 256 + threadIdx.x;
  if (e >= ET) return;
  int s, d; edge_sd(ei, e, s, d);
  #pragma unroll
  for (int h = 0; h < 2; ++h) {
    float a = av_s[s * 2 + h] + av_d[d * 2 + h];
    a = a > 0.f ? a : 0.2f * a;
    float ex = expf(a - segmax[d * 2 + h]);
    wbuf[e * 2 + h] = ex;
    atomicAdd(&segsum[d * 2 + h], ex);
  }
}
__global__ void csr_count(const int* __restrict__ ei, int* __restrict__ deg) {
  int e = blockIdx.x * 256 + threadIdx.x;
  if (e >= ET) return;
  int s, d; edge_sd(ei, e, s, d);
  atomicAdd(&deg[d], 1);
}
__global__ __launch_bounds__(1024)
void csr_scan(const int* __restrict__ deg, int* __restrict__ rowptr, int* __restrict__ fillc) {
  __shared__ int sums[1024];
  const int t = threadIdx.x;
  const int base = t * 16;
  int loc[16]; int s = 0;
  #pragma unroll
  for (int k = 0; k < 16; ++k) { loc[k] = deg[base + k]; s += loc[k]; }
  sums[t] = s;
  __syncthreads();
  for (int off = 1; off < 1024; off <<= 1) {
    int v = (t >= off) ? sums[t - off] : 0;
    __syncthreads();
    sums[t] += v;
    __syncthreads();
  }
  int run = sums[t] - s;
  #pragma unroll
  for (int k = 0; k < 16; ++k) { rowptr[base + k] = run; fillc[base + k] = run; run += loc[k]; }
  if (t == 1023) rowptr[NT] = sums[1023];
}
__global__ void csr_fill(const int* __restrict__ ei, int* __restrict__ fillc, int* __restrict__ eids) {
  int e = blockIdx.x * 256 + threadIdx.x;
  if (e >= ET) return;
  int s, d; edge_sd(ei, e, s, d);
  int pos = atomicAdd(&fillc[d], 1);
  eids[pos] = e;
}
template<int CT>
__global__ __launch_bounds__(256)
void agg_k(const int* __restrict__ rowptr, const int* __restrict__ eids, const int* __restrict__ ei,
           const bfu* __restrict__ h, const float* __restrict__ wbuf,
           const float* __restrict__ segsum, float* __restrict__ agg)
{
  const int n = blockIdx.x, tid = threadIdx.x;
  const float inv0 = 1.f / (segsum[n * 2 + 0] + 1e-16f);
  const float inv1 = 1.f / (segsum[n * 2 + 1] + 1e-16f);
  float a0 = 0.f, a1 = 0.f;
  const int beg = rowptr[n], end = rowptr[n + 1];
  for (int idx = beg; idx < end; ++idx) {
    int e = eids[idx];
    int s, d; edge_sd(ei, e, s, d);
    float w0 = wbuf[e * 2 + 0] * inv0;
    float w1 = wbuf[e * 2 + 1] * inv1;
    if (CT == 512) {
      a0 = fmaf(w0, b2f(h[(size_t)s * 512 + tid]), a0);
      a1 = fmaf(w1, b2f(h[(size_t)s * 512 + 256 + tid]), a1);
    } else {
      float wv = tid < 128 ? w0 : w1;
      a0 = fmaf(wv, b2f(h[(size_t)s * 256 + tid]), a0);
    }
  }
  if (CT == 512) {
    agg[(size_t)n * 512 + tid] = a0;
    agg[(size_t)n * 512 + 256 + tid] = a1;
  } else {
    agg[(size_t)n * 256 + tid] = a0;
  }
}

// ---------------- LayerNorm over 256, write f32 y ----------------
__global__ __launch_bounds__(256)
void ln_k(const float* __restrict__ x, const float* __restrict__ g, const float* __restrict__ bta,
          float* __restrict__ y)
{
  const int r = blockIdx.x, tid = threadIdx.x;
  float v = x[(size_t)r * 256 + tid];
  float s = v;
  #pragma unroll
  for (int off = 32; off; off >>= 1) s += __shfl_xor(s, off);
  __shared__ float red[4], red2[4];
  const int w = tid >> 6, lane = tid & 63;
  if (lane == 0) red[w] = s;
  __syncthreads();
  float mu = (red[0] + red[1] + red[2] + red[3]) * (1.f / 256.f);
  float dv = v - mu;
  float q2 = dv * dv;
  #pragma unroll
  for (int off = 32; off; off >>= 1) q2 += __shfl_xor(q2, off);
  if (lane == 0) red2[w] = q2;
  __syncthreads();
  float var = (red2[0] + red2[1] + red2[2] + red2[3]) * (1.f / 256.f);
  y[(size_t)r * 256 + tid] = dv * rsqrtf(var + 1e-6f) * g[tid] + bta[tid];
}

extern "C" void kernel_launch(void* const* d_in, const int* in_sizes, int n_in,
                              void* d_out, int out_size, void* d_ws, size_t ws_size,
                              hipStream_t stream)
{
  const float* q   = (const float*)d_in[0];
  const float* kin = (const float*)d_in[1];
  const float* vin = (const float*)d_in[2];
  const int*   ei  = (const int*)d_in[3];
  const float* Wq  = (const float*)d_in[4];
  const float* Wk  = (const float*)d_in[5];
  const float* Wv  = (const float*)d_in[6];
  const float* Wfc = (const float*)d_in[7];
  const float* g1W = (const float*)d_in[8],  *g1as = (const float*)d_in[9],  *g1ad = (const float*)d_in[10], *g1b = (const float*)d_in[11];
  const float* l1W = (const float*)d_in[12], *l1b = (const float*)d_in[13];
  const float* g2W = (const float*)d_in[14], *g2as = (const float*)d_in[15], *g2ad = (const float*)d_in[16], *g2b = (const float*)d_in[17];
  const float* l2W = (const float*)d_in[18], *l2b = (const float*)d_in[19];
  const float* g3W = (const float*)d_in[20], *g3as = (const float*)d_in[21], *g3ad = (const float*)d_in[22], *g3b = (const float*)d_in[23];
  const float* l3W = (const float*)d_in[24], *l3b = (const float*)d_in[25];
  const float* lng = (const float*)d_in[26], *lnb = (const float*)d_in[27];

  // ---- d_out regions (f32 output) ----
  float* ybuf = (float*)d_out;                          // y: NT*256 f32 = 16.78 MB
  float* attn_out = ybuf + (size_t)NT * 256;            // attn: 32*1024*1024 f32 = 134.2 MB
  bfu* catb = (bfu*)d_out;                              // bf16 [NT][256] in first half of y region

  // scratch in attn region (dead before attn_s overwrites it): ~62 MB < 134 MB
  char* ap = (char*)attn_out;
  auto take_a = [&](size_t bytes) -> void* {
    void* r = (void*)ap; ap += (bytes + 255) & ~(size_t)255; return r;
  };
  bfu* q_bf = (bfu*)take_a((size_t)NT * 256 * 2);
  bfu* k_bf = (bfu*)take_a((size_t)NT * 256 * 2);
  bfu* v_bf = (bfu*)take_a((size_t)NT * 256 * 2);
  float* aggb   = (float*)take_a((size_t)NT * 512 * 4);
  float* avs    = (float*)take_a((size_t)NT * 2 * 4);
  float* avd    = (float*)take_a((size_t)NT * 2 * 4);
  float* segmax = (float*)take_a((size_t)NT * 2 * 4);
  float* segsum = (float*)take_a((size_t)NT * 2 * 4);
  float* wbuf   = (float*)take_a((size_t)ET * 2 * 4);
  int* deg    = (int*)take_a((size_t)NT * 4);
  int* rowptr = (int*)take_a((size_t)(NT + 1) * 4);
  int* fillc  = (int*)take_a((size_t)NT * 4);
  int* eids   = (int*)take_a((size_t)ET * 4);

  // ---- d_ws (~52.6 MB) ----
  char* p = (char*)d_ws;
  auto take = [&](size_t bytes) -> void* {
    void* r = (void*)p; p += (bytes + 255) & ~(size_t)255; return r;
  };
  bfu* hbuf = (bfu*)take((size_t)NT * 512 * 2);   // 8.39M elems
  bfu* x1   = (bfu*)take((size_t)NT * 512 * 2);
  bfu* x2   = (bfu*)take((size_t)NT * 512 * 2);
  bfu* WqT  = (bfu*)take(32768 * 2);
  bfu* WkT  = (bfu*)take(32768 * 2);
  bfu* WvT  = (bfu*)take(32768 * 2);
  bfu* WfcT = (bfu*)take(65536 * 2);
  bfu* g1Wt = (bfu*)take(131072 * 2);
  bfu* l1Wt = (bfu*)take(131072 * 2);
  bfu* g2Wt = (bfu*)take(262144 * 2);
  bfu* l2Wt = (bfu*)take(262144 * 2);
  bfu* g3Wt = (bfu*)take(131072 * 2);
  bfu* l3Wt = (bfu*)take(65536 * 2);

  // hbuf dead after layer-3 agg -> alias for attention operands (6M <= 8.39M elems)
  bfu* qh2  = hbuf;                          // [32][1024][64]
  bfu* khb2 = hbuf + (size_t)2 * 1024 * 1024;
  bfu* vt   = hbuf + (size_t)4 * 1024 * 1024; // [32][64][1024]
  // x1 dead after layer-2 gemms -> prelng alias
  float* prelng = (float*)x1;

  const int EB = (ET + 255) / 256;
  const int SB = (NT * 2 + 255) / 256;
  const int zs = 0;

  // input + weight conversions
  aconv_k<<<4096, 256, 0, stream>>>(q, q_bf, NT * 64);
  aconv_k<<<4096, 256, 0, stream>>>(kin, k_bf, NT * 64);
  aconv_k<<<4096, 256, 0, stream>>>(vin, v_bf, NT * 64);
  wconv_k<<<128, 256, 0, stream>>>(Wq, WqT, 256, 128, 0.125f);   // attn scale folded in
  wconv_k<<<128, 256, 0, stream>>>(Wk, WkT, 256, 128, 1.f);
  wconv_k<<<128, 256, 0, stream>>>(Wv, WvT, 256, 128, 1.f);
  wconv_k<<<256, 256, 0, stream>>>(Wfc, WfcT, 256, 256, 1.f);
  wconv_k<<<512, 256, 0, stream>>>(g1W, g1Wt, 256, 512, 1.f);
  wconv_k<<<512, 256, 0, stream>>>(l1W, l1Wt, 256, 512, 1.f);
  wconv_k<<<1024, 256, 0, stream>>>(g2W, g2Wt, 512, 512, 1.f);
  wconv_k<<<1024, 256, 0, stream>>>(l2W, l2Wt, 512, 512, 1.f);
  wconv_k<<<512, 256, 0, stream>>>(g3W, g3Wt, 512, 256, 1.f);
  wconv_k<<<256, 256, 0, stream>>>(l3W, l3Wt, 512, 128, 1.f);

  // CSR build
  zero_i<<<(NT + 255) / 256, 256, 0, stream>>>(deg, NT);
  csr_count<<<EB, 256, 0, stream>>>(ei, deg);
  csr_scan<<<1, 1024, 0, stream>>>(deg, rowptr, fillc);
  csr_fill<<<EB, 256, 0, stream>>>(ei, fillc, eids);

  // ---- GAT layer 1 ----
  mgemm<0><<<dim3(4, 128), 256, 0, stream>>>(q_bf, 256, zs, g1Wt, 256, zs, 256, hbuf, nullptr, 512, zs, nullptr, nullptr, nullptr, 0, nullptr);
  alpha_k<256><<<NT, 256, 0, stream>>>(hbuf, g1as, g1ad, avs, avd);
  init_seg<<<SB, 256, 0, stream>>>(segmax, segsum);
  edge_max<<<EB, 256, 0, stream>>>(ei, avs, avd, segmax);
  edge_exp<<<EB, 256, 0, stream>>>(ei, avs, avd, segmax, wbuf, segsum);
  agg_k<512><<<NT, 256, 0, stream>>>(rowptr, eids, ei, hbuf, wbuf, segsum, aggb);
  mgemm<1><<<dim3(4, 128), 256, 0, stream>>>(q_bf, 256, zs, l1Wt, 256, zs, 256, x1, nullptr, 512, zs, l1b, g1b, aggb, 512, nullptr);

  // ---- GAT layer 2 ----
  mgemm<0><<<dim3(4, 128), 256, 0, stream>>>(x1, 512, zs, g2Wt, 512, zs, 512, hbuf, nullptr, 512, zs, nullptr, nullptr, nullptr, 0, nullptr);
  alpha_k<256><<<NT, 256, 0, stream>>>(hbuf, g2as, g2ad, avs, avd);
  init_seg<<<SB, 256, 0, stream>>>(segmax, segsum);
  edge_max<<<EB, 256, 0, stream>>>(ei, avs, avd, segmax);
  edge_exp<<<EB, 256, 0, stream>>>(ei, avs, avd, segmax, wbuf, segsum);
  agg_k<512><<<NT, 256, 0, stream>>>(rowptr, eids, ei, hbuf, wbuf, segsum, aggb);
  mgemm<1><<<dim3(4, 128), 256, 0, stream>>>(x1, 512, zs, l2Wt, 512, zs, 512, x2, nullptr, 512, zs, l2b, g2b, aggb, 512, nullptr);

  // ---- GAT layer 3 -> catb[:,0:128] ----
  mgemm<0><<<dim3(2, 128), 256, 0, stream>>>(x2, 512, zs, g3Wt, 512, zs, 512, hbuf, nullptr, 256, zs, nullptr, nullptr, nullptr, 0, nullptr);
  alpha_k<128><<<NT, 256, 0, stream>>>(hbuf, g3as, g3ad, avs, avd);
  init_seg<<<SB, 256, 0, stream>>>(segmax, segsum);
  edge_max<<<EB, 256, 0, stream>>>(ei, avs, avd, segmax);
  edge_exp<<<EB, 256, 0, stream>>>(ei, avs, avd, segmax, wbuf, segsum);
  agg_k<256><<<NT, 256, 0, stream>>>(rowptr, eids, ei, hbuf, wbuf, segsum, aggb);
  mgemm<2><<<dim3(1, 128), 256, 0, stream>>>(x2, 512, zs, l3Wt, 512, zs, 512, catb, nullptr, 256, zs, l3b, g3b, aggb, 256, nullptr);
  // hbuf now dead -> qh2/khb2/vt; GAT scratch + q/k/v_bf dead after projections below

  // ---- q/k/v projections (head-split layouts) ----
  mgemm<6><<<dim3(1, 128), 256, 0, stream>>>(q_bf, 256, zs, WqT, 256, zs, 256, qh2, nullptr, 0, zs, nullptr, nullptr, nullptr, 0, nullptr);
  mgemm<6><<<dim3(1, 128), 256, 0, stream>>>(k_bf, 256, zs, WkT, 256, zs, 256, khb2, nullptr, 0, zs, nullptr, nullptr, nullptr, 0, nullptr);
  mgemm<5><<<dim3(1, 128), 256, 0, stream>>>(v_bf, 256, zs, WvT, 256, zs, 256, vt, nullptr, 0, zs, nullptr, nullptr, nullptr, 0, nullptr);

  // ---- attention: S = Q K^T (f32, batched over 32 bh) -> softmax in place -> PV ----
  mgemm<4><<<dim3(8, 8, 32), 256, 0, stream>>>(qh2, 64, 65536LL, khb2, 64, 65536LL, 64, nullptr, attn_out, 1024, 1048576LL, nullptr, nullptr, nullptr, 0, nullptr);
  sm_k<<<8192, 256, 0, stream>>>(attn_out);
  pv_k<<<dim3(16, 32), 256, 0, stream>>>(attn_out, vt, catb);

  // ---- final FC + residual + LN ----
  mgemm<3><<<dim3(2, 128), 256, 0, stream>>>(catb, 256, zs, WfcT, 256, zs, 256, nullptr, prelng, 256, zs, nullptr, nullptr, nullptr, 0, q);
  ln_k<<<NT, 256, 0, stream>>>(prelng, lng, lnb, ybuf);
}

// Round 8
// 614.561 us; speedup vs baseline: 3.1600x; 1.0988x over previous
//
#include <hip/hip_runtime.h>

#define BSZ 16
#define NNODE 1024
#define NT (BSZ*NNODE)      // 16384 total nodes
#define EG 131072            // graph edges (before self loops)
#define ET (EG+NT)           // 147456 edges incl self loops

typedef unsigned short bfu;  // raw bf16
typedef __attribute__((ext_vector_type(8))) short short8v;   // 8 bf16 (4 VGPRs)
typedef __attribute__((ext_vector_type(4))) float f32x4;     // MFMA accum

typedef __attribute__((address_space(1))) const unsigned gU32;
typedef __attribute__((address_space(3))) unsigned lU32;
#define GLL16(gp, lp) __builtin_amdgcn_global_load_lds((gU32*)(gp), (lU32*)(lp), 16, 0, 0)

__device__ __forceinline__ float b2f(unsigned u) { return __uint_as_float(u << 16); }
__device__ __forceinline__ bfu f2b(float f) {
  unsigned u = __float_as_uint(f);
  u += 0x7fffu + ((u >> 16) & 1u);
  return (bfu)(u >> 16);
}
__device__ __forceinline__ void edge_sd(const int* __restrict__ ei, int e, int& s, int& d) {
  if (e < EG) { s = ei[e]; d = ei[EG + e]; } else { s = e - EG; d = e - EG; }
}
// chunk swizzle (involution): spreads the 4 k8-chunks of each row across bank groups
__device__ __forceinline__ int swz(int c) {
  int r = c >> 2;
  return (c & ~3) | ((c & 3) ^ ((r & 3) ^ ((r >> 2) & 3)));
}

// ============ MFMA GEMM: C[M,N] = A[M,K](bf16) x Bt[N,K](bf16)^T ============
// 128x128 tile, BK=32, 4 waves (2x2 of 64x64), 16x16x32 bf16, global_load_lds staging.
// EPI 0: bf16 out = acc (z-batched)
// EPI 1: bf16 out = elu(acc + b1[c] + b2[c] + agg[r*aggld+c])
// EPI 2: bf16 out = acc + b1[c] + b2[c] + 0.5*(agg[..c]+agg[..128+c])   (layer3 head-mean)
// EPI 3: f32 out  = acc + resid[r*ldo+c]                                 (pre-LN)
// EPI 4: f32 out  = acc (z-batched)          (attn scores)
// EPI 5: bf16 vt[bh][d][node] transposed-V   (projection)
// EPI 6: bf16 qh2/khb2 [bh][node][64]        (projection)
template<int EPI>
__global__ __launch_bounds__(256)
void mgemm(const bfu* __restrict__ A, int lda, long long sA,
           const bfu* __restrict__ Bt, int ldb, long long sB,
           int K,
           bfu* __restrict__ outb, float* __restrict__ outf, int ldo, long long sO,
           const float* __restrict__ b1, const float* __restrict__ b2,
           const bfu* __restrict__ agg, int aggld,
           const float* __restrict__ resid)
{
  __shared__ bfu As[128 * 32];
  __shared__ bfu Bs[128 * 32];
  const int tid = threadIdx.x;
  const int z = blockIdx.z;
  const int n0 = blockIdx.x * 128, r0 = blockIdx.y * 128;
  const bfu* Az = A + (size_t)z * sA;
  const bfu* Bz = Bt + (size_t)z * sB;

  const int w = tid >> 6, l = tid & 63;
  const int wr = w >> 1, wc = w & 1;
  const int lr = l & 15;
  const int k8 = l >> 4;

  f32x4 acc[4][4] = {};

  // staging: LDS slot tid / tid+256 receive (swizzled) global chunks
  const int s0c = swz(tid), s1c = swz(tid + 256);
  const bfu* ga0 = Az + (size_t)(r0 + (s0c >> 2)) * lda + (s0c & 3) * 8;
  const bfu* ga1 = Az + (size_t)(r0 + (s1c >> 2)) * lda + (s1c & 3) * 8;
  const bfu* gb0 = Bz + (size_t)(n0 + (s0c >> 2)) * ldb + (s0c & 3) * 8;
  const bfu* gb1 = Bz + (size_t)(n0 + (s1c >> 2)) * ldb + (s1c & 3) * 8;
  bfu* la0 = As + tid * 8;
  bfu* la1 = As + (tid + 256) * 8;
  bfu* lb0 = Bs + tid * 8;
  bfu* lb1 = Bs + (tid + 256) * 8;

  for (int k0 = 0; k0 < K; k0 += 32) {
    __syncthreads();
    GLL16(ga0, la0); GLL16(ga1, la1);
    GLL16(gb0, lb0); GLL16(gb1, lb1);
    ga0 += 32; ga1 += 32; gb0 += 32; gb1 += 32;
    __syncthreads();
    short8v af[4], bfr[4];
    #pragma unroll
    for (int mi = 0; mi < 4; ++mi) {
      const int R = wr * 64 + mi * 16 + lr;
      af[mi] = *(const short8v*)(As + swz(R * 4 + k8) * 8);
    }
    #pragma unroll
    for (int ni = 0; ni < 4; ++ni) {
      const int R = wc * 64 + ni * 16 + lr;
      bfr[ni] = *(const short8v*)(Bs + swz(R * 4 + k8) * 8);
    }
    #pragma unroll
    for (int mi = 0; mi < 4; ++mi)
      #pragma unroll
      for (int ni = 0; ni < 4; ++ni)
        acc[mi][ni] = __builtin_amdgcn_mfma_f32_16x16x32_bf16(af[mi], bfr[ni], acc[mi][ni], 0, 0, 0);
  }

  const int rr = k8 * 4;
  #pragma unroll
  for (int mi = 0; mi < 4; ++mi) {
    #pragma unroll
    for (int ni = 0; ni < 4; ++ni) {
      #pragma unroll
      for (int i = 0; i < 4; ++i) {
        const int r = r0 + wr * 64 + mi * 16 + rr + i;
        const int cc = n0 + wc * 64 + ni * 16 + lr;
        float val = acc[mi][ni][i];
        if (EPI == 0) {
          outb[(size_t)z * sO + (size_t)r * ldo + cc] = f2b(val);
        } else if (EPI == 1) {
          val += b1[cc] + b2[cc] + b2f(agg[(size_t)r * aggld + cc]);
          val = val > 0.f ? val : expm1f(val);
          outb[(size_t)r * ldo + cc] = f2b(val);
        } else if (EPI == 2) {
          val += b1[cc] + b2[cc]
               + 0.5f * (b2f(agg[(size_t)r * aggld + cc]) + b2f(agg[(size_t)r * aggld + 128 + cc]));
          outb[(size_t)r * ldo + cc] = f2b(val);
        } else if (EPI == 3) {
          outf[(size_t)r * ldo + cc] = val + resid[(size_t)r * ldo + cc];
        } else if (EPI == 4) {
          outf[(size_t)z * sO + (size_t)r * ldo + cc] = val;
        } else if (EPI == 5) {
          outb[((size_t)((r >> 10) * 2 + (cc >> 6))) * 65536 + (size_t)(cc & 63) * 1024 + (r & 1023)] = f2b(val);
        } else { // EPI == 6
          outb[((size_t)((r >> 10) * 2 + (cc >> 6))) * 65536 + (size_t)(r & 1023) * 64 + (cc & 63)] = f2b(val);
        }
      }
    }
  }
}

// ============ PV: O[1024,64] = P(bf16)[1024,1024] x vt[64,1024]^T, per bh ============
// 128x64 tile, 4 waves (4x1, 32 rows each), gll staging, same swizzle.
__global__ __launch_bounds__(256)
void pv_k(const bfu* __restrict__ Pb, const bfu* __restrict__ vt, bfu* __restrict__ catb)
{
  __shared__ bfu As[128 * 32];
  __shared__ bfu Bs[64 * 32];
  const int tid = threadIdx.x;
  const int bh = blockIdx.z;
  const int r0 = blockIdx.y * 128;
  const bfu* Az = Pb + (size_t)bh * 1048576;
  const bfu* Bz = vt + (size_t)bh * 65536;
  const int w = tid >> 6, l = tid & 63;
  const int lr = l & 15, k8 = l >> 4;

  f32x4 acc[2][4] = {};

  const int s0c = swz(tid), s1c = swz(tid + 256);
  const bfu* ga0 = Az + (size_t)(r0 + (s0c >> 2)) * 1024 + (s0c & 3) * 8;
  const bfu* ga1 = Az + (size_t)(r0 + (s1c >> 2)) * 1024 + (s1c & 3) * 8;
  const bfu* gb0 = Bz + (size_t)(s0c >> 2) * 1024 + (s0c & 3) * 8;
  bfu* la0 = As + tid * 8;
  bfu* la1 = As + (tid + 256) * 8;
  bfu* lb0 = Bs + tid * 8;

  for (int k0 = 0; k0 < 1024; k0 += 32) {
    __syncthreads();
    GLL16(ga0, la0); GLL16(ga1, la1); GLL16(gb0, lb0);
    ga0 += 32; ga1 += 32; gb0 += 32;
    __syncthreads();
    short8v af[2], bfr[4];
    #pragma unroll
    for (int mi = 0; mi < 2; ++mi) {
      const int R = w * 32 + mi * 16 + lr;
      af[mi] = *(const short8v*)(As + swz(R * 4 + k8) * 8);
    }
    #pragma unroll
    for (int ni = 0; ni < 4; ++ni) {
      const int R = ni * 16 + lr;
      bfr[ni] = *(const short8v*)(Bs + swz(R * 4 + k8) * 8);
    }
    #pragma unroll
    for (int mi = 0; mi < 2; ++mi)
      #pragma unroll
      for (int ni = 0; ni < 4; ++ni)
        acc[mi][ni] = __builtin_amdgcn_mfma_f32_16x16x32_bf16(af[mi], bfr[ni], acc[mi][ni], 0, 0, 0);
  }

  const int b = bh >> 1, h = bh & 1;
  const int rr = k8 * 4;
  #pragma unroll
  for (int mi = 0; mi < 2; ++mi) {
    #pragma unroll
    for (int ni = 0; ni < 4; ++ni) {
      #pragma unroll
      for (int i = 0; i < 4; ++i) {
        const int qn = r0 + w * 32 + mi * 16 + rr + i;
        const int d = ni * 16 + lr;
        catb[((size_t)(b * 1024 + qn)) * 256 + 128 + h * 64 + d] = f2b(acc[mi][ni][i]);
      }
    }
  }
}

// ============ row softmax: f32 S in place -> f32 P, plus bf16 P copy ============
__global__ __launch_bounds__(256)
void sm_k(float* __restrict__ P, bfu* __restrict__ Pb)
{
  const int w = threadIdx.x >> 6, l = threadIdx.x & 63;
  const size_t R = (size_t)blockIdx.x * 4 + w;
  float* row = P + R * 1024;
  bfu* brow = Pb + R * 1024;
  float v[16];
  #pragma unroll
  for (int j = 0; j < 4; ++j) {
    float4 t = *(const float4*)(row + l * 16 + j * 4);
    v[j*4+0] = t.x; v[j*4+1] = t.y; v[j*4+2] = t.z; v[j*4+3] = t.w;
  }
  float mx = v[0];
  #pragma unroll
  for (int i = 1; i < 16; ++i) mx = fmaxf(mx, v[i]);
  #pragma unroll
  for (int off = 32; off; off >>= 1) mx = fmaxf(mx, __shfl_xor(mx, off));
  float sum = 0.f;
  #pragma unroll
  for (int i = 0; i < 16; ++i) { v[i] = expf(v[i] - mx); sum += v[i]; }
  #pragma unroll
  for (int off = 32; off; off >>= 1) sum += __shfl_xor(sum, off);
  const float inv = 1.f / sum;
  #pragma unroll
  for (int i = 0; i < 16; ++i) v[i] *= inv;
  #pragma unroll
  for (int j = 0; j < 4; ++j) {
    float4 o;
    o.x = v[j*4+0]; o.y = v[j*4+1]; o.z = v[j*4+2]; o.w = v[j*4+3];
    *(float4*)(row + l * 16 + j * 4) = o;
  }
  uint4 p0, p1;
  p0.x = (unsigned)f2b(v[0])  | ((unsigned)f2b(v[1])  << 16);
  p0.y = (unsigned)f2b(v[2])  | ((unsigned)f2b(v[3])  << 16);
  p0.z = (unsigned)f2b(v[4])  | ((unsigned)f2b(v[5])  << 16);
  p0.w = (unsigned)f2b(v[6])  | ((unsigned)f2b(v[7])  << 16);
  p1.x = (unsigned)f2b(v[8])  | ((unsigned)f2b(v[9])  << 16);
  p1.y = (unsigned)f2b(v[10]) | ((unsigned)f2b(v[11]) << 16);
  p1.z = (unsigned)f2b(v[12]) | ((unsigned)f2b(v[13]) << 16);
  p1.w = (unsigned)f2b(v[14]) | ((unsigned)f2b(v[15]) << 16);
  *(uint4*)(brow + l * 16) = p0;
  *(uint4*)(brow + l * 16 + 8) = p1;
}

// ============ merged conversions ============
__global__ __launch_bounds__(256)
void aconv3_k(const float* __restrict__ q, const float* __restrict__ k, const float* __restrict__ v,
              bfu* __restrict__ qo, bfu* __restrict__ ko, bfu* __restrict__ vo, int n4)
{
  const int i = blockIdx.x * 256 + threadIdx.x;
  if (i >= n4) return;
  const float* src = blockIdx.y == 0 ? q : (blockIdx.y == 1 ? k : v);
  bfu* dst = blockIdx.y == 0 ? qo : (blockIdx.y == 1 ? ko : vo);
  float4 x = ((const float4*)src)[i];
  uint2 o;
  o.x = (unsigned)f2b(x.x) | ((unsigned)f2b(x.y) << 16);
  o.y = (unsigned)f2b(x.z) | ((unsigned)f2b(x.w) << 16);
  ((uint2*)dst)[i] = o;
}

// all W[K][N] f32 -> Wt[N][K] bf16 concatenated at `out` (Wq gets 0.125 scale)
__global__ __launch_bounds__(256)
void wconv_all(const float* __restrict__ Wq, const float* __restrict__ Wk, const float* __restrict__ Wv,
               const float* __restrict__ Wfc, const float* __restrict__ g1W, const float* __restrict__ l1W,
               const float* __restrict__ g2W, const float* __restrict__ l2W, const float* __restrict__ g3W,
               const float* __restrict__ l3W, bfu* __restrict__ out)
{
  const int idx = blockIdx.x * 256 + threadIdx.x;
  const float* src; int kb, N, base; float sc = 1.f;
  if (idx < 98304)        { int wi = idx >> 15; base = wi << 15; src = wi == 0 ? Wq : (wi == 1 ? Wk : Wv); kb = 8; N = 128; if (wi == 0) sc = 0.125f; }
  else if (idx < 163840)  { base = 98304;  src = Wfc; kb = 8; N = 256; }
  else if (idx < 294912)  { base = 163840; src = g1W; kb = 8; N = 512; }
  else if (idx < 425984)  { base = 294912; src = l1W; kb = 8; N = 512; }
  else if (idx < 688128)  { base = 425984; src = g2W; kb = 9; N = 512; }
  else if (idx < 950272)  { base = 688128; src = l2W; kb = 9; N = 512; }
  else if (idx < 1081344) { base = 950272; src = g3W; kb = 9; N = 256; }
  else if (idx < 1146880) { base = 1081344; src = l3W; kb = 9; N = 128; }
  else return;
  const int local = idx - base;
  const int n = local >> kb, k = local & ((1 << kb) - 1);
  out[idx] = f2b(src[(size_t)k * N + n] * sc);
}

// ---------------- GAT alpha ----------------
template<int CP>
__global__ __launch_bounds__(256)
void alpha_k(const bfu* __restrict__ h, const float* __restrict__ asrc, const float* __restrict__ adst,
             float* __restrict__ av_s, float* __restrict__ av_d)
{
  const int n = blockIdx.x, tid = threadIdx.x;
  const int CT = CP * 2;
  float s0 = 0.f, s1 = 0.f, d0 = 0.f, d1 = 0.f;
  for (int c = tid; c < CT; c += 256) {
    float hv = b2f(h[(size_t)n * CT + c]);
    float as = asrc[c], ad = adst[c];
    if (c < CP) { s0 = fmaf(hv, as, s0); d0 = fmaf(hv, ad, d0); }
    else        { s1 = fmaf(hv, as, s1); d1 = fmaf(hv, ad, d1); }
  }
  #pragma unroll
  for (int off = 32; off; off >>= 1) {
    s0 += __shfl_xor(s0, off); s1 += __shfl_xor(s1, off);
    d0 += __shfl_xor(d0, off); d1 += __shfl_xor(d1, off);
  }
  __shared__ float red[4][4];
  const int w = tid >> 6, lane = tid & 63;
  if (lane == 0) { red[0][w] = s0; red[1][w] = s1; red[2][w] = d0; red[3][w] = d1; }
  __syncthreads();
  if (tid == 0) {
    av_s[n * 2 + 0] = red[0][0] + red[0][1] + red[0][2] + red[0][3];
    av_s[n * 2 + 1] = red[1][0] + red[1][1] + red[1][2] + red[1][3];
    av_d[n * 2 + 0] = red[2][0] + red[2][1] + red[2][2] + red[2][3];
    av_d[n * 2 + 1] = red[3][0] + red[3][1] + red[3][2] + red[3][3];
  }
}

__global__ void zero_f(float* p, int n) {
  int i = blockIdx.x * 256 + threadIdx.x;
  if (i < n) p[i] = 0.f;
}
__global__ void zero_i(int* p, int n) {
  int i = blockIdx.x * 256 + threadIdx.x;
  if (i < n) p[i] = 0;
}

// softmax is shift-invariant; |alpha| << 88 so exp never overflows -> no max pass
__global__ void edge_exp(const int* __restrict__ ei, const float* __restrict__ av_s,
                         const float* __restrict__ av_d,
                         float* __restrict__ wbuf, float* __restrict__ segsum) {
  int e = blockIdx.x * 256 + threadIdx.x;
  if (e >= ET) return;
  int s, d; edge_sd(ei, e, s, d);
  #pragma unroll
  for (int h = 0; h < 2; ++h) {
    float a = av_s[s * 2 + h] + av_d[d * 2 + h];
    a = a > 0.f ? a : 0.2f * a;
    float ex = expf(a);
    wbuf[e * 2 + h] = ex;
    atomicAdd(&segsum[d * 2 + h], ex);
  }
}
__global__ void csr_count(const int* __restrict__ ei, int* __restrict__ deg) {
  int e = blockIdx.x * 256 + threadIdx.x;
  if (e >= ET) return;
  int s, d; edge_sd(ei, e, s, d);
  atomicAdd(&deg[d], 1);
}
__global__ __launch_bounds__(1024)
void csr_scan(const int* __restrict__ deg, int* __restrict__ rowptr, int* __restrict__ fillc) {
  __shared__ int sums[1024];
  const int t = threadIdx.x;
  const int base = t * 16;
  int loc[16]; int s = 0;
  #pragma unroll
  for (int k = 0; k < 16; ++k) { loc[k] = deg[base + k]; s += loc[k]; }
  sums[t] = s;
  __syncthreads();
  for (int off = 1; off < 1024; off <<= 1) {
    int v = (t >= off) ? sums[t - off] : 0;
    __syncthreads();
    sums[t] += v;
    __syncthreads();
  }
  int run = sums[t] - s;
  #pragma unroll
  for (int k = 0; k < 16; ++k) { rowptr[base + k] = run; fillc[base + k] = run; run += loc[k]; }
  if (t == 1023) rowptr[NT] = sums[1023];
}
__global__ void csr_fill(const int* __restrict__ ei, int* __restrict__ fillc, int* __restrict__ eids) {
  int e = blockIdx.x * 256 + threadIdx.x;
  if (e >= ET) return;
  int s, d; edge_sd(ei, e, s, d);
  int pos = atomicAdd(&fillc[d], 1);
  eids[pos] = e;
}
template<int CT>
__global__ __launch_bounds__(256)
void agg_k(const int* __restrict__ rowptr, const int* __restrict__ eids, const int* __restrict__ ei,
           const bfu* __restrict__ h, const float* __restrict__ wbuf,
           const float* __restrict__ segsum, bfu* __restrict__ agg)
{
  const int n = blockIdx.x, tid = threadIdx.x;
  const float inv0 = 1.f / (segsum[n * 2 + 0] + 1e-16f);
  const float inv1 = 1.f / (segsum[n * 2 + 1] + 1e-16f);
  float a0 = 0.f, a1 = 0.f;
  const int beg = rowptr[n], end = rowptr[n + 1];
  for (int idx = beg; idx < end; ++idx) {
    int e = eids[idx];
    int s, d; edge_sd(ei, e, s, d);
    float w0 = wbuf[e * 2 + 0] * inv0;
    float w1 = wbuf[e * 2 + 1] * inv1;
    if (CT == 512) {
      a0 = fmaf(w0, b2f(h[(size_t)s * 512 + tid]), a0);
      a1 = fmaf(w1, b2f(h[(size_t)s * 512 + 256 + tid]), a1);
    } else {
      float wv = tid < 128 ? w0 : w1;
      a0 = fmaf(wv, b2f(h[(size_t)s * 256 + tid]), a0);
    }
  }
  if (CT == 512) {
    agg[(size_t)n * 512 + tid] = f2b(a0);
    agg[(size_t)n * 512 + 256 + tid] = f2b(a1);
  } else {
    agg[(size_t)n * 256 + tid] = f2b(a0);
  }
}

// ---------------- LayerNorm over 256, write f32 y ----------------
__global__ __launch_bounds__(256)
void ln_k(const float* __restrict__ x, const float* __restrict__ g, const float* __restrict__ bta,
          float* __restrict__ y)
{
  const int r = blockIdx.x, tid = threadIdx.x;
  float v = x[(size_t)r * 256 + tid];
  float s = v;
  #pragma unroll
  for (int off = 32; off; off >>= 1) s += __shfl_xor(s, off);
  __shared__ float red[4], red2[4];
  const int w = tid >> 6, lane = tid & 63;
  if (lane == 0) red[w] = s;
  __syncthreads();
  float mu = (red[0] + red[1] + red[2] + red[3]) * (1.f / 256.f);
  float dv = v - mu;
  float q2 = dv * dv;
  #pragma unroll
  for (int off = 32; off; off >>= 1) q2 += __shfl_xor(q2, off);
  if (lane == 0) red2[w] = q2;
  __syncthreads();
  float var = (red2[0] + red2[1] + red2[2] + red2[3]) * (1.f / 256.f);
  y[(size_t)r * 256 + tid] = dv * rsqrtf(var + 1e-6f) * g[tid] + bta[tid];
}

extern "C" void kernel_launch(void* const* d_in, const int* in_sizes, int n_in,
                              void* d_out, int out_size, void* d_ws, size_t ws_size,
                              hipStream_t stream)
{
  const float* q   = (const float*)d_in[0];
  const float* kin = (const float*)d_in[1];
  const float* vin = (const float*)d_in[2];
  const int*   ei  = (const int*)d_in[3];
  const float* Wq  = (const float*)d_in[4];
  const float* Wk  = (const float*)d_in[5];
  const float* Wv  = (const float*)d_in[6];
  const float* Wfc = (const float*)d_in[7];
  const float* g1W = (const float*)d_in[8],  *g1as = (const float*)d_in[9],  *g1ad = (const float*)d_in[10];
  const float* l1W = (const float*)d_in[12], *l1b = (const float*)d_in[13], *g1b = (const float*)d_in[11];
  const float* g2W = (const float*)d_in[14], *g2as = (const float*)d_in[15], *g2ad = (const float*)d_in[16], *g2b = (const float*)d_in[17];
  const float* l2W = (const float*)d_in[18], *l2b = (const float*)d_in[19];
  const float* g3W = (const float*)d_in[20], *g3as = (const float*)d_in[21], *g3ad = (const float*)d_in[22], *g3b = (const float*)d_in[23];
  const float* l3W = (const float*)d_in[24], *l3b = (const float*)d_in[25];
  const float* lng = (const float*)d_in[26], *lnb = (const float*)d_in[27];

  // ---- d_out regions (f32 output) ----
  float* ybuf = (float*)d_out;                          // y: NT*256 f32
  float* attn_out = ybuf + (size_t)NT * 256;            // attn: 32M f32 = 134.2 MB
  bfu* catb = (bfu*)d_out;                              // bf16 [NT][256] in y region

  // GAT scratch in attn region (dead before mgemm<4> writes S over it)
  char* ap = (char*)attn_out;
  auto take_a = [&](size_t bytes) -> void* {
    void* r = (void*)ap; ap += (bytes + 255) & ~(size_t)255; return r;
  };
  bfu* q_bf = (bfu*)take_a((size_t)NT * 256 * 2);
  bfu* k_bf = (bfu*)take_a((size_t)NT * 256 * 2);
  bfu* v_bf = (bfu*)take_a((size_t)NT * 256 * 2);
  bfu* aggb  = (bfu*)take_a((size_t)NT * 512 * 2);
  float* avs    = (float*)take_a((size_t)NT * 2 * 4);
  float* avd    = (float*)take_a((size_t)NT * 2 * 4);
  float* segsum = (float*)take_a((size_t)NT * 2 * 4);
  float* wbuf   = (float*)take_a((size_t)ET * 2 * 4);
  int* deg    = (int*)take_a((size_t)NT * 4);
  int* rowptr = (int*)take_a((size_t)(NT + 1) * 4);
  int* fillc  = (int*)take_a((size_t)NT * 4);
  int* eids   = (int*)take_a((size_t)ET * 4);

  // ---- d_ws (~115 MB) ----
  char* p = (char*)d_ws;
  auto take = [&](size_t bytes) -> void* {
    void* r = (void*)p; p += (bytes + 255) & ~(size_t)255; return r;
  };
  bfu* hbuf = (bfu*)take((size_t)NT * 512 * 2);
  bfu* x1   = (bfu*)take((size_t)NT * 512 * 2);
  bfu* x2   = (bfu*)take((size_t)NT * 512 * 2);
  bfu* wall = (bfu*)take((size_t)1146880 * 2);           // all converted weights
  bfu* Pbuf = (bfu*)take((size_t)32 * 1048576 * 2);      // bf16 softmaxed P [32][1024][1024]

  bfu* WqT  = wall;
  bfu* WkT  = wall + 32768;
  bfu* WvT  = wall + 65536;
  bfu* WfcT = wall + 98304;
  bfu* g1Wt = wall + 163840;
  bfu* l1Wt = wall + 294912;
  bfu* g2Wt = wall + 425984;
  bfu* l2Wt = wall + 688128;
  bfu* g3Wt = wall + 950272;
  bfu* l3Wt = wall + 1081344;

  // hbuf dead after layer-3 agg -> attention operand aliases
  bfu* qh2  = hbuf;                            // [32][1024][64]
  bfu* khb2 = hbuf + (size_t)2 * 1024 * 1024;
  bfu* vt   = hbuf + (size_t)4 * 1024 * 1024;  // [32][64][1024]
  float* prelng = (float*)x1;                  // x1 dead after layer-2 gemms

  const int EB = (ET + 255) / 256;
  const int SB = (NT * 2 + 255) / 256;
  const long long zs = 0;

  // conversions (merged)
  aconv3_k<<<dim3(4096, 3), 256, 0, stream>>>(q, kin, vin, q_bf, k_bf, v_bf, NT * 64);
  wconv_all<<<4480, 256, 0, stream>>>(Wq, Wk, Wv, Wfc, g1W, l1W, g2W, l2W, g3W, l3W, wall);

  // CSR build
  zero_i<<<(NT + 255) / 256, 256, 0, stream>>>(deg, NT);
  csr_count<<<EB, 256, 0, stream>>>(ei, deg);
  csr_scan<<<1, 1024, 0, stream>>>(deg, rowptr, fillc);
  csr_fill<<<EB, 256, 0, stream>>>(ei, fillc, eids);

  // ---- GAT layer 1 ----
  mgemm<0><<<dim3(4, 128), 256, 0, stream>>>(q_bf, 256, zs, g1Wt, 256, zs, 256, hbuf, nullptr, 512, zs, nullptr, nullptr, nullptr, 0, nullptr);
  alpha_k<256><<<NT, 256, 0, stream>>>(hbuf, g1as, g1ad, avs, avd);
  zero_f<<<SB, 256, 0, stream>>>(segsum, NT * 2);
  edge_exp<<<EB, 256, 0, stream>>>(ei, avs, avd, wbuf, segsum);
  agg_k<512><<<NT, 256, 0, stream>>>(rowptr, eids, ei, hbuf, wbuf, segsum, aggb);
  mgemm<1><<<dim3(4, 128), 256, 0, stream>>>(q_bf, 256, zs, l1Wt, 256, zs, 256, x1, nullptr, 512, zs, l1b, g1b, aggb, 512, nullptr);

  // ---- GAT layer 2 ----
  mgemm<0><<<dim3(4, 128), 256, 0, stream>>>(x1, 512, zs, g2Wt, 512, zs, 512, hbuf, nullptr, 512, zs, nullptr, nullptr, nullptr, 0, nullptr);
  alpha_k<256><<<NT, 256, 0, stream>>>(hbuf, g2as, g2ad, avs, avd);
  zero_f<<<SB, 256, 0, stream>>>(segsum, NT * 2);
  edge_exp<<<EB, 256, 0, stream>>>(ei, avs, avd, wbuf, segsum);
  agg_k<512><<<NT, 256, 0, stream>>>(rowptr, eids, ei, hbuf, wbuf, segsum, aggb);
  mgemm<1><<<dim3(4, 128), 256, 0, stream>>>(x1, 512, zs, l2Wt, 512, zs, 512, x2, nullptr, 512, zs, l2b, g2b, aggb, 512, nullptr);
  // x1 now dead.

  // ---- GAT layer 3 -> catb[:,0:128] ----
  mgemm<0><<<dim3(2, 128), 256, 0, stream>>>(x2, 512, zs, g3Wt, 512, zs, 512, hbuf, nullptr, 256, zs, nullptr, nullptr, nullptr, 0, nullptr);
  alpha_k<128><<<NT, 256, 0, stream>>>(hbuf, g3as, g3ad, avs, avd);
  zero_f<<<SB, 256, 0, stream>>>(segsum, NT * 2);
  edge_exp<<<EB, 256, 0, stream>>>(ei, avs, avd, wbuf, segsum);
  agg_k<256><<<NT, 256, 0, stream>>>(rowptr, eids, ei, hbuf, wbuf, segsum, aggb);
  mgemm<2><<<dim3(1, 128), 256, 0, stream>>>(x2, 512, zs, l3Wt, 512, zs, 512, catb, nullptr, 256, zs, l3b, g3b, aggb, 256, nullptr);
  // hbuf now dead -> qh2/khb2/vt.

  // ---- q/k/v projections (head-split layouts) ----
  mgemm<6><<<dim3(1, 128), 256, 0, stream>>>(q_bf, 256, zs, WqT, 256, zs, 256, qh2, nullptr, 0, zs, nullptr, nullptr, nullptr, 0, nullptr);
  mgemm<6><<<dim3(1, 128), 256, 0, stream>>>(k_bf, 256, zs, WkT, 256, zs, 256, khb2, nullptr, 0, zs, nullptr, nullptr, nullptr, 0, nullptr);
  mgemm<5><<<dim3(1, 128), 256, 0, stream>>>(v_bf, 256, zs, WvT, 256, zs, 256, vt, nullptr, 0, zs, nullptr, nullptr, nullptr, 0, nullptr);

  // ---- attention: S f32 (output region) -> softmax in place + bf16 P copy -> PV ----
  mgemm<4><<<dim3(8, 8, 32), 256, 0, stream>>>(qh2, 64, 65536LL, khb2, 64, 65536LL, 64, nullptr, attn_out, 1024, 1048576LL, nullptr, nullptr, nullptr, 0, nullptr);
  sm_k<<<8192, 256, 0, stream>>>(attn_out, Pbuf);
  pv_k<<<dim3(1, 8, 32), 256, 0, stream>>>(Pbuf, vt, catb);

  // ---- final FC + residual + LN ----
  mgemm<3><<<dim3(2, 128), 256, 0, stream>>>(catb, 256, zs, WfcT, 256, zs, 256, nullptr, prelng, 256, zs, nullptr, nullptr, nullptr, 0, q);
  ln_k<<<NT, 256, 0, stream>>>(prelng, lng, lnb, ybuf);
}

// Round 10
// 578.144 us; speedup vs baseline: 3.3590x; 1.0630x over previous
//
#include <hip/hip_runtime.h>

#define BSZ 16
#define NNODE 1024
#define NT (BSZ*NNODE)      // 16384 total nodes
#define EG 131072            // graph edges (before self loops)
#define ET (EG+NT)           // 147456 edges incl self loops

typedef unsigned short bfu;  // raw bf16
typedef __attribute__((ext_vector_type(8))) short short8v;   // 8 bf16 (4 VGPRs)
typedef __attribute__((ext_vector_type(4))) float f32x4;     // MFMA accum

typedef __attribute__((address_space(1))) const unsigned gU32;
typedef __attribute__((address_space(3))) unsigned lU32;
#define GLL16(gp, lp) __builtin_amdgcn_global_load_lds((gU32*)(gp), (lU32*)(lp), 16, 0, 0)

__device__ __forceinline__ float b2f(unsigned u) { return __uint_as_float(u << 16); }
__device__ __forceinline__ bfu f2b(float f) {
  unsigned u = __float_as_uint(f);
  u += 0x7fffu + ((u >> 16) & 1u);
  return (bfu)(u >> 16);
}
__device__ __forceinline__ void unpack8(uint4 u, float* f) {
  f[0] = b2f(u.x & 0xffffu); f[1] = b2f(u.x >> 16);
  f[2] = b2f(u.y & 0xffffu); f[3] = b2f(u.y >> 16);
  f[4] = b2f(u.z & 0xffffu); f[5] = b2f(u.z >> 16);
  f[6] = b2f(u.w & 0xffffu); f[7] = b2f(u.w >> 16);
}
__device__ __forceinline__ void edge_sd(const int* __restrict__ ei, int e, int& s, int& d) {
  if (e < EG) { s = ei[e]; d = ei[EG + e]; } else { s = e - EG; d = e - EG; }
}
// chunk swizzle (involution): spreads the 4 k8-chunks of each row across bank groups
__device__ __forceinline__ int swz(int c) {
  int r = c >> 2;
  return (c & ~3) | ((c & 3) ^ ((r & 3) ^ ((r >> 2) & 3)));
}

// ============ MFMA GEMM: C[M,N] = A[M,K](bf16) x Bt[N,K](bf16)^T ============
// 128x128 tile, BK=32, 4 waves (2x2 of 64x64), 16x16x32 bf16, global_load_lds staging.
// EPI 0: bf16 out = acc; fused GAT-alpha partial dots -> atomicAdd av_s/av_d
// EPI 1: bf16 out = elu(acc + b1[c] + b2[c] + agg[r*aggld+c])
// EPI 2: bf16 out = acc + b1[c] + b2[c] + 0.5*(agg[..c]+agg[..128+c])   (layer3 head-mean)
// EPI 3: f32 out  = acc + resid[r*ldo+c]                                 (pre-LN)
// EPI 5: bf16 vt[bh][d][node] transposed-V   (projection)
// EPI 6: bf16 qh2/khb2 [bh][node][64]        (projection)
// EPI 7: bf16 out = exp(acc) (z-batched), row sums -> atomicAdd av_s     (attn expS)
template<int EPI>
__global__ __launch_bounds__(256)
void mgemm(const bfu* __restrict__ A, int lda, long long sA,
           const bfu* __restrict__ Bt, int ldb, long long sB,
           int K,
           bfu* __restrict__ outb, float* __restrict__ outf, int ldo, long long sO,
           const float* __restrict__ b1, const float* __restrict__ b2,
           const bfu* __restrict__ agg, int aggld,
           const float* __restrict__ resid,
           const float* __restrict__ asrc, const float* __restrict__ adst,
           float* __restrict__ av_s, float* __restrict__ av_d)
{
  __shared__ bfu As[128 * 32];
  __shared__ bfu Bs[128 * 32];
  const int tid = threadIdx.x;
  const int z = blockIdx.z;
  const int n0 = blockIdx.x * 128, r0 = blockIdx.y * 128;
  const bfu* Az = A + (size_t)z * sA;
  const bfu* Bz = Bt + (size_t)z * sB;

  const int w = tid >> 6, l = tid & 63;
  const int wr = w >> 1, wc = w & 1;
  const int lr = l & 15;
  const int k8 = l >> 4;

  f32x4 acc[4][4] = {};

  const int s0c = swz(tid), s1c = swz(tid + 256);
  const bfu* ga0 = Az + (size_t)(r0 + (s0c >> 2)) * lda + (s0c & 3) * 8;
  const bfu* ga1 = Az + (size_t)(r0 + (s1c >> 2)) * lda + (s1c & 3) * 8;
  const bfu* gb0 = Bz + (size_t)(n0 + (s0c >> 2)) * ldb + (s0c & 3) * 8;
  const bfu* gb1 = Bz + (size_t)(n0 + (s1c >> 2)) * ldb + (s1c & 3) * 8;
  bfu* la0 = As + tid * 8;
  bfu* la1 = As + (tid + 256) * 8;
  bfu* lb0 = Bs + tid * 8;
  bfu* lb1 = Bs + (tid + 256) * 8;

  for (int k0 = 0; k0 < K; k0 += 32) {
    __syncthreads();
    GLL16(ga0, la0); GLL16(ga1, la1);
    GLL16(gb0, lb0); GLL16(gb1, lb1);
    ga0 += 32; ga1 += 32; gb0 += 32; gb1 += 32;
    __syncthreads();
    short8v af[4], bfr[4];
    #pragma unroll
    for (int mi = 0; mi < 4; ++mi) {
      const int R = wr * 64 + mi * 16 + lr;
      af[mi] = *(const short8v*)(As + swz(R * 4 + k8) * 8);
    }
    #pragma unroll
    for (int ni = 0; ni < 4; ++ni) {
      const int R = wc * 64 + ni * 16 + lr;
      bfr[ni] = *(const short8v*)(Bs + swz(R * 4 + k8) * 8);
    }
    #pragma unroll
    for (int mi = 0; mi < 4; ++mi)
      #pragma unroll
      for (int ni = 0; ni < 4; ++ni)
        acc[mi][ni] = __builtin_amdgcn_mfma_f32_16x16x32_bf16(af[mi], bfr[ni], acc[mi][ni], 0, 0, 0);
  }

  const int rr = k8 * 4;
  float ps[4][4], pd[4][4];
  if (EPI == 0 || EPI == 7) {
    #pragma unroll
    for (int mi = 0; mi < 4; ++mi)
      #pragma unroll
      for (int i = 0; i < 4; ++i) { ps[mi][i] = 0.f; pd[mi][i] = 0.f; }
  }

  #pragma unroll
  for (int mi = 0; mi < 4; ++mi) {
    #pragma unroll
    for (int ni = 0; ni < 4; ++ni) {
      #pragma unroll
      for (int i = 0; i < 4; ++i) {
        const int r = r0 + wr * 64 + mi * 16 + rr + i;
        const int cc = n0 + wc * 64 + ni * 16 + lr;
        float val = acc[mi][ni][i];
        if (EPI == 0) {
          outb[(size_t)r * ldo + cc] = f2b(val);
          ps[mi][i] = fmaf(val, asrc[cc], ps[mi][i]);
          pd[mi][i] = fmaf(val, adst[cc], pd[mi][i]);
        } else if (EPI == 1) {
          val += b1[cc] + b2[cc] + b2f(agg[(size_t)r * aggld + cc]);
          val = val > 0.f ? val : expm1f(val);
          outb[(size_t)r * ldo + cc] = f2b(val);
        } else if (EPI == 2) {
          val += b1[cc] + b2[cc]
               + 0.5f * (b2f(agg[(size_t)r * aggld + cc]) + b2f(agg[(size_t)r * aggld + 128 + cc]));
          outb[(size_t)r * ldo + cc] = f2b(val);
        } else if (EPI == 3) {
          outf[(size_t)r * ldo + cc] = val + resid[(size_t)r * ldo + cc];
        } else if (EPI == 5) {
          outb[((size_t)((r >> 10) * 2 + (cc >> 6))) * 65536 + (size_t)(cc & 63) * 1024 + (r & 1023)] = f2b(val);
        } else if (EPI == 6) {
          outb[((size_t)((r >> 10) * 2 + (cc >> 6))) * 65536 + (size_t)(r & 1023) * 64 + (cc & 63)] = f2b(val);
        } else { // EPI == 7: expS + row-sum partials
          float e = expf(val);
          outb[(size_t)z * sO + (size_t)r * ldo + cc] = f2b(e);
          ps[mi][i] += e;
        }
      }
    }
  }

  if (EPI == 0) {
    const int hd = (n0 * 2) / ldo;   // head index, uniform per block
    #pragma unroll
    for (int mi = 0; mi < 4; ++mi) {
      #pragma unroll
      for (int i = 0; i < 4; ++i) {
        float s = ps[mi][i], d = pd[mi][i];
        #pragma unroll
        for (int m = 1; m < 16; m <<= 1) { s += __shfl_xor(s, m); d += __shfl_xor(d, m); }
        if (lr == 0) {
          const int r = r0 + wr * 64 + mi * 16 + rr + i;
          atomicAdd(&av_s[r * 2 + hd], s);
          atomicAdd(&av_d[r * 2 + hd], d);
        }
      }
    }
  } else if (EPI == 7) {
    #pragma unroll
    for (int mi = 0; mi < 4; ++mi) {
      #pragma unroll
      for (int i = 0; i < 4; ++i) {
        float s = ps[mi][i];
        #pragma unroll
        for (int m = 1; m < 16; m <<= 1) s += __shfl_xor(s, m);
        if (lr == 0) {
          const int r = r0 + wr * 64 + mi * 16 + rr + i;
          atomicAdd(&av_s[z * 1024 + r], s);
        }
      }
    }
  }
}

// ============ PV: O = (expS(bf16) x vt^T) / rowsum, per bh ============
__global__ __launch_bounds__(256)
void pv_k(const bfu* __restrict__ Pb, const bfu* __restrict__ vt,
          const float* __restrict__ rowsum, bfu* __restrict__ catb)
{
  __shared__ bfu As[128 * 32];
  __shared__ bfu Bs[64 * 32];
  const int tid = threadIdx.x;
  const int bh = blockIdx.z;
  const int r0 = blockIdx.y * 128;
  const bfu* Az = Pb + (size_t)bh * 1048576;
  const bfu* Bz = vt + (size_t)bh * 65536;
  const int w = tid >> 6, l = tid & 63;
  const int lr = l & 15, k8 = l >> 4;

  f32x4 acc[2][4] = {};

  const int s0c = swz(tid), s1c = swz(tid + 256);
  const bfu* ga0 = Az + (size_t)(r0 + (s0c >> 2)) * 1024 + (s0c & 3) * 8;
  const bfu* ga1 = Az + (size_t)(r0 + (s1c >> 2)) * 1024 + (s1c & 3) * 8;
  const bfu* gb0 = Bz + (size_t)(s0c >> 2) * 1024 + (s0c & 3) * 8;
  bfu* la0 = As + tid * 8;
  bfu* la1 = As + (tid + 256) * 8;
  bfu* lb0 = Bs + tid * 8;

  for (int k0 = 0; k0 < 1024; k0 += 32) {
    __syncthreads();
    GLL16(ga0, la0); GLL16(ga1, la1); GLL16(gb0, lb0);
    ga0 += 32; ga1 += 32; gb0 += 32;
    __syncthreads();
    short8v af[2], bfr[4];
    #pragma unroll
    for (int mi = 0; mi < 2; ++mi) {
      const int R = w * 32 + mi * 16 + lr;
      af[mi] = *(const short8v*)(As + swz(R * 4 + k8) * 8);
    }
    #pragma unroll
    for (int ni = 0; ni < 4; ++ni) {
      const int R = ni * 16 + lr;
      bfr[ni] = *(const short8v*)(Bs + swz(R * 4 + k8) * 8);
    }
    #pragma unroll
    for (int mi = 0; mi < 2; ++mi)
      #pragma unroll
      for (int ni = 0; ni < 4; ++ni)
        acc[mi][ni] = __builtin_amdgcn_mfma_f32_16x16x32_bf16(af[mi], bfr[ni], acc[mi][ni], 0, 0, 0);
  }

  const int b = bh >> 1, h = bh & 1;
  const int rr = k8 * 4;
  #pragma unroll
  for (int mi = 0; mi < 2; ++mi) {
    #pragma unroll
    for (int i = 0; i < 4; ++i) {
      const int qn = r0 + w * 32 + mi * 16 + rr + i;
      const float inv = 1.f / rowsum[bh * 1024 + qn];
      #pragma unroll
      for (int ni = 0; ni < 4; ++ni) {
        const int d = ni * 16 + lr;
        catb[((size_t)(b * 1024 + qn)) * 256 + 128 + h * 64 + d] = f2b(acc[mi][ni][i] * inv);
      }
    }
  }
}

// ============ normalize: f32 attn = bf16 expS / rowsum ============
__global__ __launch_bounds__(256)
void normk(const bfu* __restrict__ Pb, const float* __restrict__ rowsum, float* __restrict__ Pf)
{
  const int w = threadIdx.x >> 6, l = threadIdx.x & 63;
  const size_t R = (size_t)blockIdx.x * 4 + w;
  const bfu* brow = Pb + R * 1024;
  float* frow = Pf + R * 1024;
  const float inv = 1.f / rowsum[R];
  uint4 u0 = *(const uint4*)(brow + l * 16);
  uint4 u1 = *(const uint4*)(brow + l * 16 + 8);
  float v[16];
  unpack8(u0, v); unpack8(u1, v + 8);
  #pragma unroll
  for (int j = 0; j < 4; ++j) {
    float4 o;
    o.x = v[j*4+0]*inv; o.y = v[j*4+1]*inv; o.z = v[j*4+2]*inv; o.w = v[j*4+3]*inv;
    *(float4*)(frow + l * 16 + j * 4) = o;
  }
}

// ============ merged conversions ============
__global__ __launch_bounds__(256)
void aconv3_k(const float* __restrict__ q, const float* __restrict__ k, const float* __restrict__ v,
              bfu* __restrict__ qo, bfu* __restrict__ ko, bfu* __restrict__ vo, int n4)
{
  const int i = blockIdx.x * 256 + threadIdx.x;
  if (i >= n4) return;
  const float* src = blockIdx.y == 0 ? q : (blockIdx.y == 1 ? k : v);
  bfu* dst = blockIdx.y == 0 ? qo : (blockIdx.y == 1 ? ko : vo);
  float4 x = ((const float4*)src)[i];
  uint2 o;
  o.x = (unsigned)f2b(x.x) | ((unsigned)f2b(x.y) << 16);
  o.y = (unsigned)f2b(x.z) | ((unsigned)f2b(x.w) << 16);
  ((uint2*)dst)[i] = o;
}

__global__ __launch_bounds__(256)
void wconv_all(const float* __restrict__ Wq, const float* __restrict__ Wk, const float* __restrict__ Wv,
               const float* __restrict__ Wfc, const float* __restrict__ g1W, const float* __restrict__ l1W,
               const float* __restrict__ g2W, const float* __restrict__ l2W, const float* __restrict__ g3W,
               const float* __restrict__ l3W, bfu* __restrict__ out)
{
  const int idx = blockIdx.x * 256 + threadIdx.x;
  const float* src; int kb, N, base; float sc = 1.f;
  if (idx < 98304)        { int wi = idx >> 15; base = wi << 15; src = wi == 0 ? Wq : (wi == 1 ? Wk : Wv); kb = 8; N = 128; if (wi == 0) sc = 0.125f; }
  else if (idx < 163840)  { base = 98304;  src = Wfc; kb = 8; N = 256; }
  else if (idx < 294912)  { base = 163840; src = g1W; kb = 8; N = 512; }
  else if (idx < 425984)  { base = 294912; src = l1W; kb = 8; N = 512; }
  else if (idx < 688128)  { base = 425984; src = g2W; kb = 9; N = 512; }
  else if (idx < 950272)  { base = 688128; src = l2W; kb = 9; N = 512; }
  else if (idx < 1081344) { base = 950272; src = g3W; kb = 9; N = 256; }
  else if (idx < 1146880) { base = 1081344; src = l3W; kb = 9; N = 128; }
  else return;
  const int local = idx - base;
  const int n = local >> kb, k = local & ((1 << kb) - 1);
  out[idx] = f2b(src[(size_t)k * N + n] * sc);
}

__global__ void zero_f(float* p, int n) {
  int i = blockIdx.x * 256 + threadIdx.x;
  if (i < n) p[i] = 0.f;
}
__global__ void zero_i(int* p, int n) {
  int i = blockIdx.x * 256 + threadIdx.x;
  if (i < n) p[i] = 0;
}

// softmax is shift-invariant; |alpha| << 88 so exp never overflows -> no max pass
__global__ void edge_exp(const int* __restrict__ ei, const float* __restrict__ av_s,
                         const float* __restrict__ av_d,
                         float* __restrict__ wbuf, float* __restrict__ segsum) {
  int e = blockIdx.x * 256 + threadIdx.x;
  if (e >= ET) return;
  int s, d; edge_sd(ei, e, s, d);
  #pragma unroll
  for (int h = 0; h < 2; ++h) {
    float a = av_s[s * 2 + h] + av_d[d * 2 + h];
    a = a > 0.f ? a : 0.2f * a;
    float ex = expf(a);
    wbuf[e * 2 + h] = ex;
    atomicAdd(&segsum[d * 2 + h], ex);
  }
}
__global__ void csr_count(const int* __restrict__ ei, int* __restrict__ deg) {
  int e = blockIdx.x * 256 + threadIdx.x;
  if (e >= ET) return;
  int s, d; edge_sd(ei, e, s, d);
  atomicAdd(&deg[d], 1);
}
__global__ __launch_bounds__(1024)
void csr_scan(const int* __restrict__ deg, int* __restrict__ rowptr, int* __restrict__ fillc) {
  __shared__ int sums[1024];
  const int t = threadIdx.x;
  const int base = t * 16;
  int loc[16]; int s = 0;
  #pragma unroll
  for (int k = 0; k < 16; ++k) { loc[k] = deg[base + k]; s += loc[k]; }
  sums[t] = s;
  __syncthreads();
  for (int off = 1; off < 1024; off <<= 1) {
    int v = (t >= off) ? sums[t - off] : 0;
    __syncthreads();
    sums[t] += v;
    __syncthreads();
  }
  int run = sums[t] - s;
  #pragma unroll
  for (int k = 0; k < 16; ++k) { rowptr[base + k] = run; fillc[base + k] = run; run += loc[k]; }
  if (t == 1023) rowptr[NT] = sums[1023];
}
__global__ void csr_fill(const int* __restrict__ ei, int* __restrict__ fillc, int* __restrict__ eids) {
  int e = blockIdx.x * 256 + threadIdx.x;
  if (e >= ET) return;
  int s, d; edge_sd(ei, e, s, d);
  int pos = atomicAdd(&fillc[d], 1);
  eids[pos] = e;
}
template<int CT>
__global__ __launch_bounds__(256)
void agg_k(const int* __restrict__ rowptr, const int* __restrict__ eids, const int* __restrict__ ei,
           const bfu* __restrict__ h, const float* __restrict__ wbuf,
           const float* __restrict__ segsum, bfu* __restrict__ agg)
{
  const int n = blockIdx.x, tid = threadIdx.x;
  const float inv0 = 1.f / (segsum[n * 2 + 0] + 1e-16f);
  const float inv1 = 1.f / (segsum[n * 2 + 1] + 1e-16f);
  float a0 = 0.f, a1 = 0.f;
  const int beg = rowptr[n], end = rowptr[n + 1];
  for (int idx = beg; idx < end; ++idx) {
    int e = eids[idx];
    int s, d; edge_sd(ei, e, s, d);
    float w0 = wbuf[e * 2 + 0] * inv0;
    float w1 = wbuf[e * 2 + 1] * inv1;
    if (CT == 512) {
      a0 = fmaf(w0, b2f(h[(size_t)s * 512 + tid]), a0);
      a1 = fmaf(w1, b2f(h[(size_t)s * 512 + 256 + tid]), a1);
    } else {
      float wv = tid < 128 ? w0 : w1;
      a0 = fmaf(wv, b2f(h[(size_t)s * 256 + tid]), a0);
    }
  }
  if (CT == 512) {
    agg[(size_t)n * 512 + tid] = f2b(a0);
    agg[(size_t)n * 512 + 256 + tid] = f2b(a1);
  } else {
    agg[(size_t)n * 256 + tid] = f2b(a0);
  }
}

// ---------------- LayerNorm over 256, write f32 y ----------------
__global__ __launch_bounds__(256)
void ln_k(const float* __restrict__ x, const float* __restrict__ g, const float* __restrict__ bta,
          float* __restrict__ y)
{
  const int r = blockIdx.x, tid = threadIdx.x;
  float v = x[(size_t)r * 256 + tid];
  float s = v;
  #pragma unroll
  for (int off = 32; off; off >>= 1) s += __shfl_xor(s, off);
  __shared__ float red[4], red2[4];
  const int w = tid >> 6, lane = tid & 63;
  if (lane == 0) red[w] = s;
  __syncthreads();
  float mu = (red[0] + red[1] + red[2] + red[3]) * (1.f / 256.f);
  float dv = v - mu;
  float q2 = dv * dv;
  #pragma unroll
  for (int off = 32; off; off >>= 1) q2 += __shfl_xor(q2, off);
  if (lane == 0) red2[w] = q2;
  __syncthreads();
  float var = (red2[0] + red2[1] + red2[2] + red2[3]) * (1.f / 256.f);
  y[(size_t)r * 256 + tid] = dv * rsqrtf(var + 1e-6f) * g[tid] + bta[tid];
}

extern "C" void kernel_launch(void* const* d_in, const int* in_sizes, int n_in,
                              void* d_out, int out_size, void* d_ws, size_t ws_size,
                              hipStream_t stream)
{
  const float* q   = (const float*)d_in[0];
  const float* kin = (const float*)d_in[1];
  const float* vin = (const float*)d_in[2];
  const int*   ei  = (const int*)d_in[3];
  const float* Wq  = (const float*)d_in[4];
  const float* Wk  = (const float*)d_in[5];
  const float* Wv  = (const float*)d_in[6];
  const float* Wfc = (const float*)d_in[7];
  const float* g1W = (const float*)d_in[8],  *g1as = (const float*)d_in[9],  *g1ad = (const float*)d_in[10];
  const float* l1W = (const float*)d_in[12], *l1b = (const float*)d_in[13], *g1b = (const float*)d_in[11];
  const float* g2W = (const float*)d_in[14], *g2as = (const float*)d_in[15], *g2ad = (const float*)d_in[16], *g2b = (const float*)d_in[17];
  const float* l2W = (const float*)d_in[18], *l2b = (const float*)d_in[19];
  const float* g3W = (const float*)d_in[20], *g3as = (const float*)d_in[21], *g3ad = (const float*)d_in[22], *g3b = (const float*)d_in[23];
  const float* l3W = (const float*)d_in[24], *l3b = (const float*)d_in[25];
  const float* lng = (const float*)d_in[26], *lnb = (const float*)d_in[27];

  // ---- d_out regions (f32 output) ----
  float* ybuf = (float*)d_out;                          // y: NT*256 f32
  float* attn_out = ybuf + (size_t)NT * 256;            // attn: 32M f32 = 134.2 MB
  bfu* catb = (bfu*)d_out;                              // bf16 [NT][256] in y region

  // GAT scratch in attn region (dead before normk writes P over it)
  char* ap = (char*)attn_out;
  auto take_a = [&](size_t bytes) -> void* {
    void* r = (void*)ap; ap += (bytes + 255) & ~(size_t)255; return r;
  };
  bfu* q_bf = (bfu*)take_a((size_t)NT * 256 * 2);
  bfu* k_bf = (bfu*)take_a((size_t)NT * 256 * 2);
  bfu* v_bf = (bfu*)take_a((size_t)NT * 256 * 2);
  bfu* aggb  = (bfu*)take_a((size_t)NT * 512 * 2);
  float* avsd = (float*)take_a((size_t)NT * 6 * 4);     // avs | avd | segsum (zeroed together)
  float* avs    = avsd;
  float* avd    = avsd + (size_t)NT * 2;
  float* segsum = avsd + (size_t)NT * 4;
  float* wbuf   = (float*)take_a((size_t)ET * 2 * 4);
  int* deg    = (int*)take_a((size_t)NT * 4);
  int* rowptr = (int*)take_a((size_t)(NT + 1) * 4);
  int* fillc  = (int*)take_a((size_t)NT * 4);
  int* eids   = (int*)take_a((size_t)ET * 4);

  // ---- d_ws (~115 MB) ----
  char* p = (char*)d_ws;
  auto take = [&](size_t bytes) -> void* {
    void* r = (void*)p; p += (bytes + 255) & ~(size_t)255; return r;
  };
  bfu* hbuf = (bfu*)take((size_t)NT * 512 * 2);
  bfu* x1   = (bfu*)take((size_t)NT * 512 * 2);
  bfu* x2   = (bfu*)take((size_t)NT * 512 * 2);
  bfu* wall = (bfu*)take((size_t)1146880 * 2);           // all converted weights
  bfu* Pbuf = (bfu*)take((size_t)32 * 1048576 * 2);      // bf16 expS [32][1024][1024]
  float* rowsum = (float*)take((size_t)32 * 1024 * 4);   // attn row sums

  bfu* WqT  = wall;
  bfu* WkT  = wall + 32768;
  bfu* WvT  = wall + 65536;
  bfu* WfcT = wall + 98304;
  bfu* g1Wt = wall + 163840;
  bfu* l1Wt = wall + 294912;
  bfu* g2Wt = wall + 425984;
  bfu* l2Wt = wall + 688128;
  bfu* g3Wt = wall + 950272;
  bfu* l3Wt = wall + 1081344;

  // hbuf dead after layer-3 agg -> attention operand aliases
  bfu* qh2  = hbuf;                            // [32][1024][64]
  bfu* khb2 = hbuf + (size_t)2 * 1024 * 1024;
  bfu* vt   = hbuf + (size_t)4 * 1024 * 1024;  // [32][64][1024]
  float* prelng = (float*)x1;                  // x1 dead after layer-2 gemms

  const int EB = (ET + 255) / 256;
  const int ZB = (NT * 6 + 255) / 256;
  const long long zs = 0;
  #define NOAL nullptr, nullptr, nullptr, nullptr

  // conversions (merged)
  aconv3_k<<<dim3(4096, 3), 256, 0, stream>>>(q, kin, vin, q_bf, k_bf, v_bf, NT * 64);
  wconv_all<<<4480, 256, 0, stream>>>(Wq, Wk, Wv, Wfc, g1W, l1W, g2W, l2W, g3W, l3W, wall);

  // CSR build
  zero_i<<<(NT + 255) / 256, 256, 0, stream>>>(deg, NT);
  csr_count<<<EB, 256, 0, stream>>>(ei, deg);
  csr_scan<<<1, 1024, 0, stream>>>(deg, rowptr, fillc);
  csr_fill<<<EB, 256, 0, stream>>>(ei, fillc, eids);

  // ---- GAT layer 1 ----
  zero_f<<<ZB, 256, 0, stream>>>(avsd, NT * 6);
  mgemm<0><<<dim3(4, 128), 256, 0, stream>>>(q_bf, 256, zs, g1Wt, 256, zs, 256, hbuf, nullptr, 512, zs, nullptr, nullptr, nullptr, 0, nullptr, g1as, g1ad, avs, avd);
  edge_exp<<<EB, 256, 0, stream>>>(ei, avs, avd, wbuf, segsum);
  agg_k<512><<<NT, 256, 0, stream>>>(rowptr, eids, ei, hbuf, wbuf, segsum, aggb);
  mgemm<1><<<dim3(4, 128), 256, 0, stream>>>(q_bf, 256, zs, l1Wt, 256, zs, 256, x1, nullptr, 512, zs, l1b, g1b, aggb, 512, nullptr, NOAL);

  // ---- GAT layer 2 ----
  zero_f<<<ZB, 256, 0, stream>>>(avsd, NT * 6);
  mgemm<0><<<dim3(4, 128), 256, 0, stream>>>(x1, 512, zs, g2Wt, 512, zs, 512, hbuf, nullptr, 512, zs, nullptr, nullptr, nullptr, 0, nullptr, g2as, g2ad, avs, avd);
  edge_exp<<<EB, 256, 0, stream>>>(ei, avs, avd, wbuf, segsum);
  agg_k<512><<<NT, 256, 0, stream>>>(rowptr, eids, ei, hbuf, wbuf, segsum, aggb);
  mgemm<1><<<dim3(4, 128), 256, 0, stream>>>(x1, 512, zs, l2Wt, 512, zs, 512, x2, nullptr, 512, zs, l2b, g2b, aggb, 512, nullptr, NOAL);
  // x1 now dead.

  // ---- GAT layer 3 -> catb[:,0:128] ----
  zero_f<<<ZB, 256, 0, stream>>>(avsd, NT * 6);
  mgemm<0><<<dim3(2, 128), 256, 0, stream>>>(x2, 512, zs, g3Wt, 512, zs, 512, hbuf, nullptr, 256, zs, nullptr, nullptr, nullptr, 0, nullptr, g3as, g3ad, avs, avd);
  edge_exp<<<EB, 256, 0, stream>>>(ei, avs, avd, wbuf, segsum);
  agg_k<256><<<NT, 256, 0, stream>>>(rowptr, eids, ei, hbuf, wbuf, segsum, aggb);
  mgemm<2><<<dim3(1, 128), 256, 0, stream>>>(x2, 512, zs, l3Wt, 512, zs, 512, catb, nullptr, 256, zs, l3b, g3b, aggb, 256, nullptr, NOAL);
  // hbuf now dead -> qh2/khb2/vt.

  // ---- q/k/v projections (head-split layouts) ----
  mgemm<6><<<dim3(1, 128), 256, 0, stream>>>(q_bf, 256, zs, WqT, 256, zs, 256, qh2, nullptr, 0, zs, nullptr, nullptr, nullptr, 0, nullptr, NOAL);
  mgemm<6><<<dim3(1, 128), 256, 0, stream>>>(k_bf, 256, zs, WkT, 256, zs, 256, khb2, nullptr, 0, zs, nullptr, nullptr, nullptr, 0, nullptr, NOAL);
  mgemm<5><<<dim3(1, 128), 256, 0, stream>>>(v_bf, 256, zs, WvT, 256, zs, 256, vt, nullptr, 0, zs, nullptr, nullptr, nullptr, 0, nullptr, NOAL);

  // ---- attention: expS bf16 + rowsums -> normalize (f32 output) -> PV ----
  zero_f<<<128, 256, 0, stream>>>(rowsum, 32 * 1024);
  mgemm<7><<<dim3(8, 8, 32), 256, 0, stream>>>(qh2, 64, 65536LL, khb2, 64, 65536LL, 64, Pbuf, nullptr, 1024, 1048576LL, nullptr, nullptr, nullptr, 0, nullptr, nullptr, nullptr, rowsum, nullptr);
  normk<<<8192, 256, 0, stream>>>(Pbuf, rowsum, attn_out);
  pv_k<<<dim3(1, 8, 32), 256, 0, stream>>>(Pbuf, vt, rowsum, catb);

  // ---- final FC + residual + LN ----
  mgemm<3><<<dim3(2, 128), 256, 0, stream>>>(catb, 256, zs, WfcT, 256, zs, 256, nullptr, prelng, 256, zs, nullptr, nullptr, nullptr, 0, q, NOAL);
  ln_k<<<NT, 256, 0, stream>>>(prelng, lng, lnb, ybuf);
}

// Round 12
// 489.247 us; speedup vs baseline: 3.9694x; 1.1817x over previous
//
#include <hip/hip_runtime.h>

#define BSZ 16
#define NNODE 1024
#define NT (BSZ*NNODE)      // 16384 total nodes
#define EG 131072            // graph edges (before self loops)
#define ET (EG+NT)           // 147456 edges incl self loops

typedef unsigned short bfu;  // raw bf16
typedef __attribute__((ext_vector_type(8))) short short8v;   // 8 bf16 (4 VGPRs)
typedef __attribute__((ext_vector_type(4))) float f32x4;     // MFMA accum

typedef __attribute__((address_space(1))) const unsigned gU32;
typedef __attribute__((address_space(3))) unsigned lU32;
#define GLL16(gp, lp) __builtin_amdgcn_global_load_lds((gU32*)(gp), (lU32*)(lp), 16, 0, 0)

__device__ __forceinline__ float b2f(unsigned u) { return __uint_as_float(u << 16); }
__device__ __forceinline__ bfu f2b(float f) {
  unsigned u = __float_as_uint(f);
  u += 0x7fffu + ((u >> 16) & 1u);
  return (bfu)(u >> 16);
}
__device__ __forceinline__ void unpack8(uint4 u, float* f) {
  f[0] = b2f(u.x & 0xffffu); f[1] = b2f(u.x >> 16);
  f[2] = b2f(u.y & 0xffffu); f[3] = b2f(u.y >> 16);
  f[4] = b2f(u.z & 0xffffu); f[5] = b2f(u.z >> 16);
  f[6] = b2f(u.w & 0xffffu); f[7] = b2f(u.w >> 16);
}
__device__ __forceinline__ void edge_sd(const int* __restrict__ ei, int e, int& s, int& d) {
  if (e < EG) { s = ei[e]; d = ei[EG + e]; } else { s = e - EG; d = e - EG; }
}
// chunk swizzle (involution): spreads the 4 k8-chunks of each row across bank groups
__device__ __forceinline__ int swz(int c) {
  int r = c >> 2;
  return (c & ~3) | ((c & 3) ^ ((r & 3) ^ ((r >> 2) & 3)));
}

// ============ MFMA GEMM: C[M,N] = A[M,K](bf16) x Bt[N,K](bf16)^T ============
// 128x128 tile, BK=32, 4 waves (2x2 of 64x64), 16x16x32 bf16, global_load_lds staging.
// EPI 0: bf16 out = acc; GAT-alpha partials STORED to av_s/av_d[r][hd][blk][wc]
// EPI 1: bf16 out = elu(acc + b1[c] + b2[c] + agg[r*aggld+c])
// EPI 2: bf16 out = acc + b1[c] + b2[c] + 0.5*(agg[..c]+agg[..128+c])   (layer3 head-mean)
// EPI 3: f32 out  = acc + resid[r*ldo+c]                                 (pre-LN)
// EPI 7: bf16 out = exp(acc) (z-batched); row-sum partials STORED [z][r][blk][wc] (16)
// EPI 8: batched qkv projections: z<2 -> [bh][node][64] at z*2M; z==2 -> vt [bh][d][node] at 4M
template<int EPI>
__global__ __launch_bounds__(256)
void mgemm(const bfu* __restrict__ A, int lda, long long sA,
           const bfu* __restrict__ Bt, int ldb, long long sB,
           int K,
           bfu* __restrict__ outb, float* __restrict__ outf, int ldo, long long sO,
           const float* __restrict__ b1, const float* __restrict__ b2,
           const bfu* __restrict__ agg, int aggld,
           const float* __restrict__ resid,
           const float* __restrict__ asrc, const float* __restrict__ adst,
           float* __restrict__ av_s, float* __restrict__ av_d)
{
  __shared__ bfu As[128 * 32];
  __shared__ bfu Bs[128 * 32];
  const int tid = threadIdx.x;
  const int z = blockIdx.z;
  const int n0 = blockIdx.x * 128, r0 = blockIdx.y * 128;
  const bfu* Az = A + (size_t)z * sA;
  const bfu* Bz = Bt + (size_t)z * sB;

  const int w = tid >> 6, l = tid & 63;
  const int wr = w >> 1, wc = w & 1;
  const int lr = l & 15;
  const int k8 = l >> 4;

  f32x4 acc[4][4] = {};

  const int s0c = swz(tid), s1c = swz(tid + 256);
  const bfu* ga0 = Az + (size_t)(r0 + (s0c >> 2)) * lda + (s0c & 3) * 8;
  const bfu* ga1 = Az + (size_t)(r0 + (s1c >> 2)) * lda + (s1c & 3) * 8;
  const bfu* gb0 = Bz + (size_t)(n0 + (s0c >> 2)) * ldb + (s0c & 3) * 8;
  const bfu* gb1 = Bz + (size_t)(n0 + (s1c >> 2)) * ldb + (s1c & 3) * 8;
  bfu* la0 = As + tid * 8;
  bfu* la1 = As + (tid + 256) * 8;
  bfu* lb0 = Bs + tid * 8;
  bfu* lb1 = Bs + (tid + 256) * 8;

  for (int k0 = 0; k0 < K; k0 += 32) {
    __syncthreads();
    GLL16(ga0, la0); GLL16(ga1, la1);
    GLL16(gb0, lb0); GLL16(gb1, lb1);
    ga0 += 32; ga1 += 32; gb0 += 32; gb1 += 32;
    __syncthreads();
    short8v af[4], bfr[4];
    #pragma unroll
    for (int mi = 0; mi < 4; ++mi) {
      const int R = wr * 64 + mi * 16 + lr;
      af[mi] = *(const short8v*)(As + swz(R * 4 + k8) * 8);
    }
    #pragma unroll
    for (int ni = 0; ni < 4; ++ni) {
      const int R = wc * 64 + ni * 16 + lr;
      bfr[ni] = *(const short8v*)(Bs + swz(R * 4 + k8) * 8);
    }
    #pragma unroll
    for (int mi = 0; mi < 4; ++mi)
      #pragma unroll
      for (int ni = 0; ni < 4; ++ni)
        acc[mi][ni] = __builtin_amdgcn_mfma_f32_16x16x32_bf16(af[mi], bfr[ni], acc[mi][ni], 0, 0, 0);
  }

  const int rr = k8 * 4;
  float ps[4][4], pd[4][4];
  if (EPI == 0 || EPI == 7) {
    #pragma unroll
    for (int mi = 0; mi < 4; ++mi)
      #pragma unroll
      for (int i = 0; i < 4; ++i) { ps[mi][i] = 0.f; pd[mi][i] = 0.f; }
  }

  #pragma unroll
  for (int mi = 0; mi < 4; ++mi) {
    #pragma unroll
    for (int ni = 0; ni < 4; ++ni) {
      #pragma unroll
      for (int i = 0; i < 4; ++i) {
        const int r = r0 + wr * 64 + mi * 16 + rr + i;
        const int cc = n0 + wc * 64 + ni * 16 + lr;
        float val = acc[mi][ni][i];
        if (EPI == 0) {
          outb[(size_t)r * ldo + cc] = f2b(val);
          ps[mi][i] = fmaf(val, asrc[cc], ps[mi][i]);
          pd[mi][i] = fmaf(val, adst[cc], pd[mi][i]);
        } else if (EPI == 1) {
          val += b1[cc] + b2[cc] + b2f(agg[(size_t)r * aggld + cc]);
          val = val > 0.f ? val : expm1f(val);
          outb[(size_t)r * ldo + cc] = f2b(val);
        } else if (EPI == 2) {
          val += b1[cc] + b2[cc]
               + 0.5f * (b2f(agg[(size_t)r * aggld + cc]) + b2f(agg[(size_t)r * aggld + 128 + cc]));
          outb[(size_t)r * ldo + cc] = f2b(val);
        } else if (EPI == 3) {
          outf[(size_t)r * ldo + cc] = val + resid[(size_t)r * ldo + cc];
        } else if (EPI == 7) {
          float e = expf(val);
          outb[(size_t)z * sO + (size_t)r * ldo + cc] = f2b(e);
          ps[mi][i] += e;
        } else { // EPI == 8: batched q/k/v projections
          if (z < 2) {
            outb[(size_t)z * 2097152 + ((size_t)((r >> 10) * 2 + (cc >> 6))) * 65536
                 + (size_t)(r & 1023) * 64 + (cc & 63)] = f2b(val);
          } else {
            outb[4194304 + ((size_t)((r >> 10) * 2 + (cc >> 6))) * 65536
                 + (size_t)(cc & 63) * 1024 + (r & 1023)] = f2b(val);
          }
        }
      }
    }
  }

  if (EPI == 0) {
    const int half = ldo >> 1;
    const int hd = n0 / half;                 // head, uniform per block
    const int blk = (n0 & (half - 1)) >> 7;   // block index within head (0 or 1)
    #pragma unroll
    for (int mi = 0; mi < 4; ++mi) {
      #pragma unroll
      for (int i = 0; i < 4; ++i) {
        float s = ps[mi][i], d = pd[mi][i];
        #pragma unroll
        for (int m = 1; m < 16; m <<= 1) { s += __shfl_xor(s, m); d += __shfl_xor(d, m); }
        if (lr == 0) {
          const int r = r0 + wr * 64 + mi * 16 + rr + i;
          // unique slot per (block, wave-column): no race
          av_s[((size_t)r * 2 + hd) * 4 + blk * 2 + wc] = s;
          av_d[((size_t)r * 2 + hd) * 4 + blk * 2 + wc] = d;
        }
      }
    }
  } else if (EPI == 7) {
    #pragma unroll
    for (int mi = 0; mi < 4; ++mi) {
      #pragma unroll
      for (int i = 0; i < 4; ++i) {
        float s = ps[mi][i];
        #pragma unroll
        for (int m = 1; m < 16; m <<= 1) s += __shfl_xor(s, m);
        if (lr == 0) {
          const int r = r0 + wr * 64 + mi * 16 + rr + i;
          av_s[((size_t)z * 1024 + r) * 16 + ((n0 >> 7) << 1) + wc] = s;  // unique slot
        }
      }
    }
  }
}

// ============ PV: O = (expS(bf16) x vt^T) / rowsum, per bh ============
__global__ __launch_bounds__(256)
void pv_k(const bfu* __restrict__ Pb, const bfu* __restrict__ vt,
          const float* __restrict__ rowsum16, bfu* __restrict__ catb)
{
  __shared__ bfu As[128 * 32];
  __shared__ bfu Bs[64 * 32];
  const int tid = threadIdx.x;
  const int bh = blockIdx.z;
  const int r0 = blockIdx.y * 128;
  const bfu* Az = Pb + (size_t)bh * 1048576;
  const bfu* Bz = vt + (size_t)bh * 65536;
  const int w = tid >> 6, l = tid & 63;
  const int lr = l & 15, k8 = l >> 4;

  f32x4 acc[2][4] = {};

  const int s0c = swz(tid), s1c = swz(tid + 256);
  const bfu* ga0 = Az + (size_t)(r0 + (s0c >> 2)) * 1024 + (s0c & 3) * 8;
  const bfu* ga1 = Az + (size_t)(r0 + (s1c >> 2)) * 1024 + (s1c & 3) * 8;
  const bfu* gb0 = Bz + (size_t)(s0c >> 2) * 1024 + (s0c & 3) * 8;
  bfu* la0 = As + tid * 8;
  bfu* la1 = As + (tid + 256) * 8;
  bfu* lb0 = Bs + tid * 8;

  for (int k0 = 0; k0 < 1024; k0 += 32) {
    __syncthreads();
    GLL16(ga0, la0); GLL16(ga1, la1); GLL16(gb0, lb0);
    ga0 += 32; ga1 += 32; gb0 += 32;
    __syncthreads();
    short8v af[2], bfr[4];
    #pragma unroll
    for (int mi = 0; mi < 2; ++mi) {
      const int R = w * 32 + mi * 16 + lr;
      af[mi] = *(const short8v*)(As + swz(R * 4 + k8) * 8);
    }
    #pragma unroll
    for (int ni = 0; ni < 4; ++ni) {
      const int R = ni * 16 + lr;
      bfr[ni] = *(const short8v*)(Bs + swz(R * 4 + k8) * 8);
    }
    #pragma unroll
    for (int mi = 0; mi < 2; ++mi)
      #pragma unroll
      for (int ni = 0; ni < 4; ++ni)
        acc[mi][ni] = __builtin_amdgcn_mfma_f32_16x16x32_bf16(af[mi], bfr[ni], acc[mi][ni], 0, 0, 0);
  }

  const int b = bh >> 1, h = bh & 1;
  const int rr = k8 * 4;
  #pragma unroll
  for (int mi = 0; mi < 2; ++mi) {
    #pragma unroll
    for (int i = 0; i < 4; ++i) {
      const int qn = r0 + w * 32 + mi * 16 + rr + i;
      float sm = 0.f;
      #pragma unroll
      for (int j = 0; j < 16; ++j) sm += rowsum16[((size_t)bh * 1024 + qn) * 16 + j];
      const float inv = 1.f / sm;
      #pragma unroll
      for (int ni = 0; ni < 4; ++ni) {
        const int d = ni * 16 + lr;
        catb[((size_t)(b * 1024 + qn)) * 256 + 128 + h * 64 + d] = f2b(acc[mi][ni][i] * inv);
      }
    }
  }
}

// ============ normalize: f32 attn = bf16 expS / rowsum ============
__global__ __launch_bounds__(256)
void normk(const bfu* __restrict__ Pb, const float* __restrict__ rowsum16, float* __restrict__ Pf)
{
  const int w = threadIdx.x >> 6, l = threadIdx.x & 63;
  const size_t R = (size_t)blockIdx.x * 4 + w;
  const bfu* brow = Pb + R * 1024;
  float* frow = Pf + R * 1024;
  float sm = 0.f;
  #pragma unroll
  for (int j = 0; j < 16; ++j) sm += rowsum16[R * 16 + j];
  const float inv = 1.f / sm;
  uint4 u0 = *(const uint4*)(brow + l * 16);
  uint4 u1 = *(const uint4*)(brow + l * 16 + 8);
  float v[16];
  unpack8(u0, v); unpack8(u1, v + 8);
  #pragma unroll
  for (int j = 0; j < 4; ++j) {
    float4 o;
    o.x = v[j*4+0]*inv; o.y = v[j*4+1]*inv; o.z = v[j*4+2]*inv; o.w = v[j*4+3]*inv;
    *(float4*)(frow + l * 16 + j * 4) = o;
  }
}

// ============ merged conversions ============
__global__ __launch_bounds__(256)
void aconv3_k(const float* __restrict__ q, const float* __restrict__ k, const float* __restrict__ v,
              bfu* __restrict__ qo, bfu* __restrict__ ko, bfu* __restrict__ vo, int n4)
{
  const int i = blockIdx.x * 256 + threadIdx.x;
  if (i >= n4) return;
  const float* src = blockIdx.y == 0 ? q : (blockIdx.y == 1 ? k : v);
  bfu* dst = blockIdx.y == 0 ? qo : (blockIdx.y == 1 ? ko : vo);
  float4 x = ((const float4*)src)[i];
  uint2 o;
  o.x = (unsigned)f2b(x.x) | ((unsigned)f2b(x.y) << 16);
  o.y = (unsigned)f2b(x.z) | ((unsigned)f2b(x.w) << 16);
  ((uint2*)dst)[i] = o;
}

__global__ __launch_bounds__(256)
void wconv_all(const float* __restrict__ Wq, const float* __restrict__ Wk, const float* __restrict__ Wv,
               const float* __restrict__ Wfc, const float* __restrict__ g1W, const float* __restrict__ l1W,
               const float* __restrict__ g2W, const float* __restrict__ l2W, const float* __restrict__ g3W,
               const float* __restrict__ l3W, bfu* __restrict__ out)
{
  const int idx = blockIdx.x * 256 + threadIdx.x;
  const float* src; int kb, N, base; float sc = 1.f;
  if (idx < 98304)        { int wi = idx >> 15; base = wi << 15; src = wi == 0 ? Wq : (wi == 1 ? Wk : Wv); kb = 8; N = 128; if (wi == 0) sc = 0.125f; }
  else if (idx < 163840)  { base = 98304;  src = Wfc; kb = 8; N = 256; }
  else if (idx < 294912)  { base = 163840; src = g1W; kb = 8; N = 512; }
  else if (idx < 425984)  { base = 294912; src = l1W; kb = 8; N = 512; }
  else if (idx < 688128)  { base = 425984; src = g2W; kb = 9; N = 512; }
  else if (idx < 950272)  { base = 688128; src = l2W; kb = 9; N = 512; }
  else if (idx < 1081344) { base = 950272; src = g3W; kb = 9; N = 256; }
  else if (idx < 1146880) { base = 1081344; src = l3W; kb = 9; N = 128; }
  else return;
  const int local = idx - base;
  const int n = local >> kb, k = local & ((1 << kb) - 1);
  out[idx] = f2b(src[(size_t)k * N + n] * sc);
}

__global__ void zero_i(int* p, int n) {
  int i = blockIdx.x * 256 + threadIdx.x;
  if (i < n) p[i] = 0;
}

// ---------------- CSR build ----------------
__global__ void csr_count(const int* __restrict__ ei, int* __restrict__ deg) {
  int e = blockIdx.x * 256 + threadIdx.x;
  if (e >= ET) return;
  int s, d; edge_sd(ei, e, s, d);
  atomicAdd(&deg[d], 1);
}
__global__ __launch_bounds__(1024)
void csr_scan(const int* __restrict__ deg, int* __restrict__ rowptr, int* __restrict__ fillc) {
  __shared__ int sums[1024];
  const int t = threadIdx.x;
  const int base = t * 16;
  int loc[16]; int s = 0;
  #pragma unroll
  for (int k = 0; k < 16; ++k) { loc[k] = deg[base + k]; s += loc[k]; }
  sums[t] = s;
  __syncthreads();
  for (int off = 1; off < 1024; off <<= 1) {
    int v = (t >= off) ? sums[t - off] : 0;
    __syncthreads();
    sums[t] += v;
    __syncthreads();
  }
  int run = sums[t] - s;
  #pragma unroll
  for (int k = 0; k < 16; ++k) { rowptr[base + k] = run; fillc[base + k] = run; run += loc[k]; }
  if (t == 1023) rowptr[NT] = sums[1023];
}
// stores SRC node directly (not edge id)
__global__ void csr_fill(const int* __restrict__ ei, int* __restrict__ fillc, int* __restrict__ srcs) {
  int e = blockIdx.x * 256 + threadIdx.x;
  if (e >= ET) return;
  int s, d; edge_sd(ei, e, s, d);
  int pos = atomicAdd(&fillc[d], 1);
  srcs[pos] = s;
}

// ---------------- fused GAT softmax + aggregation ----------------
// per node: recompute edge alpha from partials, exp, accumulate h, normalize.
// partial layout: [node][head(2)][blk(2)][wc(2)] = 8 f32 per node
template<int CT, int NBLK>  // CT: 512 (layers 1/2) or 256 (layer 3); NBLK: col-blocks/head
__global__ __launch_bounds__(256)
void aggf_k(const int* __restrict__ rowptr, const int* __restrict__ srcs,
            const float* __restrict__ avsp, const float* __restrict__ avdp,
            const bfu* __restrict__ h, bfu* __restrict__ agg)
{
  const int n = blockIdx.x, tid = threadIdx.x;
  float ad0 = avdp[(size_t)n * 8 + 0] + avdp[(size_t)n * 8 + 1];
  float ad1 = avdp[(size_t)n * 8 + 4] + avdp[(size_t)n * 8 + 5];
  if (NBLK > 1) {
    ad0 += avdp[(size_t)n * 8 + 2] + avdp[(size_t)n * 8 + 3];
    ad1 += avdp[(size_t)n * 8 + 6] + avdp[(size_t)n * 8 + 7];
  }
  float a0 = 0.f, a1 = 0.f, sum0 = 0.f, sum1 = 0.f;
  const int beg = rowptr[n], end = rowptr[n + 1];
  for (int idx = beg; idx < end; ++idx) {
    const int s = srcs[idx];
    float as0 = avsp[(size_t)s * 8 + 0] + avsp[(size_t)s * 8 + 1];
    float as1 = avsp[(size_t)s * 8 + 4] + avsp[(size_t)s * 8 + 5];
    if (NBLK > 1) {
      as0 += avsp[(size_t)s * 8 + 2] + avsp[(size_t)s * 8 + 3];
      as1 += avsp[(size_t)s * 8 + 6] + avsp[(size_t)s * 8 + 7];
    }
    float al0 = as0 + ad0; al0 = al0 > 0.f ? al0 : 0.2f * al0;
    float al1 = as1 + ad1; al1 = al1 > 0.f ? al1 : 0.2f * al1;
    const float e0 = expf(al0), e1 = expf(al1);
    sum0 += e0; sum1 += e1;
    if (CT == 512) {
      a0 = fmaf(e0, b2f(h[(size_t)s * 512 + tid]), a0);
      a1 = fmaf(e1, b2f(h[(size_t)s * 512 + 256 + tid]), a1);
    } else {
      const float ev = tid < 128 ? e0 : e1;
      a0 = fmaf(ev, b2f(h[(size_t)s * 256 + tid]), a0);
    }
  }
  if (CT == 512) {
    agg[(size_t)n * 512 + tid] = f2b(a0 / (sum0 + 1e-16f));
    agg[(size_t)n * 512 + 256 + tid] = f2b(a1 / (sum1 + 1e-16f));
  } else {
    const float sv = tid < 128 ? sum0 : sum1;
    agg[(size_t)n * 256 + tid] = f2b(a0 / (sv + 1e-16f));
  }
}

// ---------------- LayerNorm over 256, write f32 y ----------------
__global__ __launch_bounds__(256)
void ln_k(const float* __restrict__ x, const float* __restrict__ g, const float* __restrict__ bta,
          float* __restrict__ y)
{
  const int r = blockIdx.x, tid = threadIdx.x;
  float v = x[(size_t)r * 256 + tid];
  float s = v;
  #pragma unroll
  for (int off = 32; off; off >>= 1) s += __shfl_xor(s, off);
  __shared__ float red[4], red2[4];
  const int w = tid >> 6, lane = tid & 63;
  if (lane == 0) red[w] = s;
  __syncthreads();
  float mu = (red[0] + red[1] + red[2] + red[3]) * (1.f / 256.f);
  float dv = v - mu;
  float q2 = dv * dv;
  #pragma unroll
  for (int off = 32; off; off >>= 1) q2 += __shfl_xor(q2, off);
  if (lane == 0) red2[w] = q2;
  __syncthreads();
  float var = (red2[0] + red2[1] + red2[2] + red2[3]) * (1.f / 256.f);
  y[(size_t)r * 256 + tid] = dv * rsqrtf(var + 1e-6f) * g[tid] + bta[tid];
}

extern "C" void kernel_launch(void* const* d_in, const int* in_sizes, int n_in,
                              void* d_out, int out_size, void* d_ws, size_t ws_size,
                              hipStream_t stream)
{
  const float* q   = (const float*)d_in[0];
  const float* kin = (const float*)d_in[1];
  const float* vin = (const float*)d_in[2];
  const int*   ei  = (const int*)d_in[3];
  const float* Wq  = (const float*)d_in[4];
  const float* Wk  = (const float*)d_in[5];
  const float* Wv  = (const float*)d_in[6];
  const float* Wfc = (const float*)d_in[7];
  const float* g1W = (const float*)d_in[8],  *g1as = (const float*)d_in[9],  *g1ad = (const float*)d_in[10];
  const float* l1W = (const float*)d_in[12], *l1b = (const float*)d_in[13], *g1b = (const float*)d_in[11];
  const float* g2W = (const float*)d_in[14], *g2as = (const float*)d_in[15], *g2ad = (const float*)d_in[16], *g2b = (const float*)d_in[17];
  const float* l2W = (const float*)d_in[18], *l2b = (const float*)d_in[19];
  const float* g3W = (const float*)d_in[20], *g3as = (const float*)d_in[21], *g3ad = (const float*)d_in[22], *g3b = (const float*)d_in[23];
  const float* l3W = (const float*)d_in[24], *l3b = (const float*)d_in[25];
  const float* lng = (const float*)d_in[26], *lnb = (const float*)d_in[27];

  // ---- d_out regions (f32 output) ----
  float* ybuf = (float*)d_out;                          // y: NT*256 f32
  float* attn_out = ybuf + (size_t)NT * 256;            // attn: 32M f32 = 134.2 MB
  bfu* catb = (bfu*)d_out;                              // bf16 [NT][256] in y region

  // GAT scratch in attn region (dead before normk writes P over it)
  char* ap = (char*)attn_out;
  auto take_a = [&](size_t bytes) -> void* {
    void* r = (void*)ap; ap += (bytes + 255) & ~(size_t)255; return r;
  };
  bfu* q_bf = (bfu*)take_a((size_t)NT * 256 * 2);   // NOTE: q_bf/k_bf/v_bf contiguous (EPI 8 relies on stride NT*256)
  bfu* k_bf = (bfu*)take_a((size_t)NT * 256 * 2);
  bfu* v_bf = (bfu*)take_a((size_t)NT * 256 * 2);
  bfu* aggb  = (bfu*)take_a((size_t)NT * 512 * 2);
  float* avsp = (float*)take_a((size_t)NT * 8 * 4);  // alpha-src partials [r][hd][blk][wc]
  float* avdp = (float*)take_a((size_t)NT * 8 * 4);  // alpha-dst partials
  int* deg    = (int*)take_a((size_t)NT * 4);
  int* rowptr = (int*)take_a((size_t)(NT + 1) * 4);
  int* fillc  = (int*)take_a((size_t)NT * 4);
  int* srcs   = (int*)take_a((size_t)ET * 4);

  // ---- d_ws (~117 MB) ----
  char* p = (char*)d_ws;
  auto take = [&](size_t bytes) -> void* {
    void* r = (void*)p; p += (bytes + 255) & ~(size_t)255; return r;
  };
  bfu* hbuf = (bfu*)take((size_t)NT * 512 * 2);
  bfu* x1   = (bfu*)take((size_t)NT * 512 * 2);
  bfu* x2   = (bfu*)take((size_t)NT * 512 * 2);
  bfu* wall = (bfu*)take((size_t)1146880 * 2);               // all converted weights
  bfu* Pbuf = (bfu*)take((size_t)32 * 1048576 * 2);          // bf16 expS [32][1024][1024]
  float* rowsum16 = (float*)take((size_t)32 * 1024 * 16 * 4);// attn row-sum partials [bh][r][16]

  bfu* WqT  = wall;                 // WqT/WkT/WvT contiguous, stride 32768 (EPI 8)
  bfu* WfcT = wall + 98304;
  bfu* g1Wt = wall + 163840;
  bfu* l1Wt = wall + 294912;
  bfu* g2Wt = wall + 425984;
  bfu* l2Wt = wall + 688128;
  bfu* g3Wt = wall + 950272;
  bfu* l3Wt = wall + 1081344;

  // hbuf dead after layer-3 agg -> attention operand aliases
  bfu* qh2  = hbuf;                            // [32][1024][64] (EPI 8 z=0 base)
  bfu* khb2 = hbuf + (size_t)2 * 1024 * 1024;
  bfu* vt   = hbuf + (size_t)4 * 1024 * 1024;  // [32][64][1024]
  float* prelng = (float*)x1;                  // x1 dead after layer-2 gemms

  const int EB = (ET + 255) / 256;
  const long long zs = 0;
  #define NOAL nullptr, nullptr, nullptr, nullptr

  // conversions (merged)
  aconv3_k<<<dim3(4096, 3), 256, 0, stream>>>(q, kin, vin, q_bf, k_bf, v_bf, NT * 64);
  wconv_all<<<4480, 256, 0, stream>>>(Wq, Wk, Wv, Wfc, g1W, l1W, g2W, l2W, g3W, l3W, wall);

  // CSR build (srcs stored directly)
  zero_i<<<(NT + 255) / 256, 256, 0, stream>>>(deg, NT);
  csr_count<<<EB, 256, 0, stream>>>(ei, deg);
  csr_scan<<<1, 1024, 0, stream>>>(deg, rowptr, fillc);
  csr_fill<<<EB, 256, 0, stream>>>(ei, fillc, srcs);

  // ---- GAT layer 1 ----
  mgemm<0><<<dim3(4, 128), 256, 0, stream>>>(q_bf, 256, zs, g1Wt, 256, zs, 256, hbuf, nullptr, 512, zs, nullptr, nullptr, nullptr, 0, nullptr, g1as, g1ad, avsp, avdp);
  aggf_k<512, 2><<<NT, 256, 0, stream>>>(rowptr, srcs, avsp, avdp, hbuf, aggb);
  mgemm<1><<<dim3(4, 128), 256, 0, stream>>>(q_bf, 256, zs, l1Wt, 256, zs, 256, x1, nullptr, 512, zs, l1b, g1b, aggb, 512, nullptr, NOAL);

  // ---- GAT layer 2 ----
  mgemm<0><<<dim3(4, 128), 256, 0, stream>>>(x1, 512, zs, g2Wt, 512, zs, 512, hbuf, nullptr, 512, zs, nullptr, nullptr, nullptr, 0, nullptr, g2as, g2ad, avsp, avdp);
  aggf_k<512, 2><<<NT, 256, 0, stream>>>(rowptr, srcs, avsp, avdp, hbuf, aggb);
  mgemm<1><<<dim3(4, 128), 256, 0, stream>>>(x1, 512, zs, l2Wt, 512, zs, 512, x2, nullptr, 512, zs, l2b, g2b, aggb, 512, nullptr, NOAL);
  // x1 now dead.

  // ---- GAT layer 3 -> catb[:,0:128] ----
  mgemm<0><<<dim3(2, 128), 256, 0, stream>>>(x2, 512, zs, g3Wt, 512, zs, 512, hbuf, nullptr, 256, zs, nullptr, nullptr, nullptr, 0, nullptr, g3as, g3ad, avsp, avdp);
  aggf_k<256, 1><<<NT, 256, 0, stream>>>(rowptr, srcs, avsp, avdp, hbuf, aggb);
  mgemm<2><<<dim3(1, 128), 256, 0, stream>>>(x2, 512, zs, l3Wt, 512, zs, 512, catb, nullptr, 256, zs, l3b, g3b, aggb, 256, nullptr, NOAL);
  // hbuf now dead -> qh2/khb2/vt.

  // ---- q/k/v projections, batched over z (head-split layouts) ----
  mgemm<8><<<dim3(1, 128, 3), 256, 0, stream>>>(q_bf, 256, (long long)NT * 256, WqT, 256, 32768LL, 256, qh2, nullptr, 0, zs, nullptr, nullptr, nullptr, 0, nullptr, NOAL);

  // ---- attention: expS bf16 + rowsum partials -> normalize (f32 output) -> PV ----
  mgemm<7><<<dim3(8, 8, 32), 256, 0, stream>>>(qh2, 64, 65536LL, khb2, 64, 65536LL, 64, Pbuf, nullptr, 1024, 1048576LL, nullptr, nullptr, nullptr, 0, nullptr, nullptr, nullptr, rowsum16, nullptr);
  normk<<<8192, 256, 0, stream>>>(Pbuf, rowsum16, attn_out);
  pv_k<<<dim3(1, 8, 32), 256, 0, stream>>>(Pbuf, vt, rowsum16, catb);

  // ---- final FC + residual + LN ----
  mgemm<3><<<dim3(2, 128), 256, 0, stream>>>(catb, 256, zs, WfcT, 256, zs, 256, nullptr, prelng, 256, zs, nullptr, nullptr, nullptr, 0, q, NOAL);
  ln_k<<<NT, 256, 0, stream>>>(prelng, lng, lnb, ybuf);
}